// Round 7
// baseline (654.763 us; speedup 1.0000x reference)
//
#include <hip/hip_runtime.h>
#include <hip/hip_bf16.h>

#define NNODES 50000
#define NEDGES 600000
#define NGRAPHS 512
#define BN_EPS 1e-5f

typedef short bf16x8 __attribute__((ext_vector_type(8)));
typedef float f32x4 __attribute__((ext_vector_type(4)));

// split fp32 -> hi/lo bf16 (RNE); hi+lo carries ~16 mantissa bits
__device__ __forceinline__ void bf_split(float x, ushort& h, ushort& l) {
    __hip_bfloat16 bh = __float2bfloat16(x);
    float r = x - __bfloat162float(bh);
    __hip_bfloat16 bl = __float2bfloat16(r);
    h = __builtin_bit_cast(ushort, bh);
    l = __builtin_bit_cast(ushort, bl);
}

// ------------------------------------------------------------------- prep
// One kernel: zero pooled (blocks 0..191, float4), zero counts (192..387),
// zero barrier vars (388), wsplit 6 matrices (389..484).
__global__ __launch_bounds__(256) void prep_kernel(
    float* __restrict__ pooled, int* __restrict__ counts, int* __restrict__ bar,
    const float* W0, const float* W1, const float* W2, const float* W3,
    const float* W4, const float* W5, ushort* __restrict__ hi, ushort* __restrict__ lo) {
    int b = blockIdx.x, t = threadIdx.x;
    if (b < 192) {                                  // pooled: 512*384 = 196608 fl
        ((float4*)pooled)[b * 256 + t] = make_float4(0.f, 0.f, 0.f, 0.f);
    } else if (b < 388) {                           // counts: 50000 ints
        int i = (b - 192) * 256 + t;
        if (i < NNODES) counts[i] = 0;
    } else if (b == 388) {
        if (t < 8) bar[t] = 0;
    } else {                                        // wsplit: 96 blocks
        int wb = b - 389;
        const float* Ws[6] = {W0, W1, W2, W3, W4, W5};
        const float* W = Ws[wb >> 4];
        ushort* h = hi + (size_t)(wb >> 4) * 16384;
        ushort* l = lo + (size_t)(wb >> 4) * 16384;
        int chunk = wb & 15;
#pragma unroll
        for (int i = 0; i < 4; i++) {
            int idx = chunk * 1024 + i * 256 + t;
            int n = idx >> 7, k = idx & 127;
            ushort hh, ll;
            bf_split(W[k * 128 + n], hh, ll);
            h[n * 128 + k] = hh;
            l[n * 128 + k] = ll;
        }
    }
}

// ---------------------------------------------------------------- CSR build
__global__ __launch_bounds__(256) void hist_kernel(const int* __restrict__ dst,
                                                   int* __restrict__ counts, int E) {
    int i = blockIdx.x * 256 + threadIdx.x;
    if (i < E) atomicAdd(&counts[dst[i]], 1);
}

__global__ __launch_bounds__(256) void scan1_kernel(const int* __restrict__ counts,
                                                    int* __restrict__ partials, int n) {
    __shared__ int s[256];
    int i = blockIdx.x * 256 + threadIdx.x;
    int v = (i < n) ? counts[i] : 0;
    s[threadIdx.x] = v;
    __syncthreads();
    for (int off = 128; off > 0; off >>= 1) {
        if (threadIdx.x < off) s[threadIdx.x] += s[threadIdx.x + off];
        __syncthreads();
    }
    if (threadIdx.x == 0) partials[blockIdx.x] = s[0];
}

__global__ __launch_bounds__(256) void scan2_kernel(int* __restrict__ partials, int nb,
                                                    int* __restrict__ row_ptr, int total) {
    __shared__ int s[256];
    int t = threadIdx.x;
    int v = (t < nb) ? partials[t] : 0;
    s[t] = v;
    __syncthreads();
    for (int off = 1; off < 256; off <<= 1) {
        int nv = (t >= off) ? s[t - off] : 0;
        __syncthreads();
        s[t] += nv;
        __syncthreads();
    }
    if (t < nb) partials[t] = s[t] - v;   // exclusive
    if (t == 0) row_ptr[NNODES] = total;
}

__global__ __launch_bounds__(256) void scan3_kernel(const int* __restrict__ counts,
                                                    const int* __restrict__ partials,
                                                    int* __restrict__ row_ptr,
                                                    int* __restrict__ cursor, int n) {
    __shared__ int s[256];
    int i = blockIdx.x * 256 + threadIdx.x;
    int v = (i < n) ? counts[i] : 0;
    s[threadIdx.x] = v;
    __syncthreads();
    for (int off = 1; off < 256; off <<= 1) {
        int nv = (threadIdx.x >= (unsigned)off) ? s[threadIdx.x - off] : 0;
        __syncthreads();
        s[threadIdx.x] += nv;
        __syncthreads();
    }
    if (i < n) {
        int ex = partials[blockIdx.x] + s[threadIdx.x] - v;  // exclusive
        row_ptr[i] = ex;
        cursor[i] = ex;
    }
}

__global__ __launch_bounds__(256) void scatter_kernel(const int* __restrict__ src,
                                                      const int* __restrict__ dst,
                                                      int* __restrict__ cursor,
                                                      int* __restrict__ esrc, int E) {
    int i = blockIdx.x * 256 + threadIdx.x;
    if (i < E) {
        int p = atomicAdd(&cursor[dst[i]], 1);
        esrc[p] = src[i];
    }
}

// ------------------------------------------------------------ fused layer
// out = act( BN_ReLU( (x + sum_nbr x) @ W1 ) @ W2 + b2 ), 32 nodes/block.
// R6's 64-row tile had ~12 waves/CU with 8 loads in flight = ~96/CU -> gather
// at 2.06 TB/s (0.56x of the 3.7 ceiling). 32-row tile: LDS 17.4KB -> 6-8
// blocks/CU (24-32 waves/CU) + unroll-8 gather (16 outstanding/wave) ->
// >300 in-flight/CU -> saturate. Wave tile 16x64 (1x4 of 16x16x32).
#define HSTR 136                 // LDS row stride (ushorts): frag reads 8/bank-group
#define PPLANE (32 * HSTR)       // 4352
template <bool RELU_OUT>
__global__ __launch_bounds__(256) void layer_kernel(
    const float* __restrict__ xin, const int* __restrict__ rp,
    const int* __restrict__ esrc,
    const ushort* __restrict__ W1hi, const ushort* __restrict__ W1lo,
    const ushort* __restrict__ W2hi, const ushort* __restrict__ W2lo,
    const float* __restrict__ b1, const float* __restrict__ gm,
    const float* __restrict__ bt, const float* __restrict__ rm,
    const float* __restrict__ rv, const float* __restrict__ b2,
    float* __restrict__ out, int M) {
    __shared__ __align__(16) ushort smem[2 * PPLANE];   // 17408 B
#define SH(p_, o_) smem[(p_)*PPLANE + (o_)]
    const int t = threadIdx.x;
    const int lane = t & 63;
    const int wv = t >> 6;
    const int wr = wv >> 1, wc = wv & 1;     // 2x2 waves: 16 rows x 64 cols each
    const int row0 = blockIdx.x * 32;
    const int g = lane >> 4, c = lane & 15;
    const int q = lane & 31;

    // ---------------- phase 0: gather + split into LDS A planes
    const float4* x4 = (const float4*)xin;
#pragma unroll 1
    for (int pass = 0; pass < 4; pass++) {
        int nt = wv * 8 + pass * 2 + (lane >> 5);
        int node = row0 + nt;
        float4 acc = make_float4(0.f, 0.f, 0.f, 0.f);
        if (node < M) {
            acc = x4[(size_t)node * 32 + q];   // self term (eps=0)
            int beg = rp[node], end = rp[node + 1];
            int e = beg;
            for (; e + 8 <= end; e += 8) {     // 8 rows in flight per half-wave
                int i0 = esrc[e],     i1 = esrc[e + 1], i2 = esrc[e + 2], i3 = esrc[e + 3];
                int i4 = esrc[e + 4], i5 = esrc[e + 5], i6 = esrc[e + 6], i7 = esrc[e + 7];
                float4 v0 = x4[(size_t)i0 * 32 + q];
                float4 v1 = x4[(size_t)i1 * 32 + q];
                float4 v2 = x4[(size_t)i2 * 32 + q];
                float4 v3 = x4[(size_t)i3 * 32 + q];
                float4 v4 = x4[(size_t)i4 * 32 + q];
                float4 v5 = x4[(size_t)i5 * 32 + q];
                float4 v6 = x4[(size_t)i6 * 32 + q];
                float4 v7 = x4[(size_t)i7 * 32 + q];
                acc.x += ((v0.x + v1.x) + (v2.x + v3.x)) + ((v4.x + v5.x) + (v6.x + v7.x));
                acc.y += ((v0.y + v1.y) + (v2.y + v3.y)) + ((v4.y + v5.y) + (v6.y + v7.y));
                acc.z += ((v0.z + v1.z) + (v2.z + v3.z)) + ((v4.z + v5.z) + (v6.z + v7.z));
                acc.w += ((v0.w + v1.w) + (v2.w + v3.w)) + ((v4.w + v5.w) + (v6.w + v7.w));
            }
            for (; e + 2 <= end; e += 2) {
                int i0 = esrc[e], i1 = esrc[e + 1];
                float4 v0 = x4[(size_t)i0 * 32 + q];
                float4 v1 = x4[(size_t)i1 * 32 + q];
                acc.x += v0.x + v1.x; acc.y += v0.y + v1.y;
                acc.z += v0.z + v1.z; acc.w += v0.w + v1.w;
            }
            for (; e < end; e++) {
                int i0 = esrc[e];
                float4 v = x4[(size_t)i0 * 32 + q];
                acc.x += v.x; acc.y += v.y; acc.z += v.z; acc.w += v.w;
            }
        }
        ushort4 hh, ll;
        bf_split(acc.x, hh.x, ll.x);
        bf_split(acc.y, hh.y, ll.y);
        bf_split(acc.z, hh.z, ll.z);
        bf_split(acc.w, hh.w, ll.w);
        *(ushort4*)&SH(0, nt * HSTR + q * 4) = hh;
        *(ushort4*)&SH(1, nt * HSTR + q * 4) = ll;
    }
    __syncthreads();

    // ---------------- phase 1: A @ W1
    f32x4 acc[4];
#pragma unroll
    for (int j = 0; j < 4; j++) acc[j] = (f32x4){0.f, 0.f, 0.f, 0.f};

#pragma unroll
    for (int kb = 0; kb < 4; kb++) {
        bf16x8 bh[4], bl[4];
#pragma unroll
        for (int ct = 0; ct < 4; ct++) {
            const size_t wo = (size_t)(wc * 64 + ct * 16 + c) * 128 + kb * 32 + g * 8;
            bh[ct] = *(const bf16x8*)(W1hi + wo);
            bl[ct] = *(const bf16x8*)(W1lo + wo);
        }
        int off = (wr * 16 + c) * HSTR + kb * 32 + g * 8;
        bf16x8 ah = *(bf16x8*)&SH(0, off);
        bf16x8 al = *(bf16x8*)&SH(1, off);
#pragma unroll
        for (int ct = 0; ct < 4; ct++) {
            acc[ct] = __builtin_amdgcn_mfma_f32_16x16x32_bf16(ah, bh[ct], acc[ct], 0, 0, 0);
            acc[ct] = __builtin_amdgcn_mfma_f32_16x16x32_bf16(ah, bl[ct], acc[ct], 0, 0, 0);
            acc[ct] = __builtin_amdgcn_mfma_f32_16x16x32_bf16(al, bh[ct], acc[ct], 0, 0, 0);
        }
    }
    __syncthreads();   // all A reads done -> H may overwrite

    // ---------------- BN + ReLU -> H planes (same LDS)
    {
#pragma unroll
        for (int ct = 0; ct < 4; ct++) {
            int n = wc * 64 + ct * 16 + c;
            float s = gm[n] * rsqrtf(rv[n] + BN_EPS);
            float ca = (b1[n] - rm[n]) * s + bt[n];
#pragma unroll
            for (int r = 0; r < 4; r++) {
                int row = wr * 16 + g * 4 + r;
                float v = fmaxf(acc[ct][r] * s + ca, 0.f);
                ushort hh, ll;
                bf_split(v, hh, ll);
                SH(0, row * HSTR + n) = hh;
                SH(1, row * HSTR + n) = ll;
            }
        }
    }
    __syncthreads();

    // ---------------- phase 2: H @ W2
#pragma unroll
    for (int j = 0; j < 4; j++) acc[j] = (f32x4){0.f, 0.f, 0.f, 0.f};

#pragma unroll
    for (int kb = 0; kb < 4; kb++) {
        bf16x8 bh[4], bl[4];
#pragma unroll
        for (int ct = 0; ct < 4; ct++) {
            const size_t wo = (size_t)(wc * 64 + ct * 16 + c) * 128 + kb * 32 + g * 8;
            bh[ct] = *(const bf16x8*)(W2hi + wo);
            bl[ct] = *(const bf16x8*)(W2lo + wo);
        }
        int off = (wr * 16 + c) * HSTR + kb * 32 + g * 8;
        bf16x8 ah = *(bf16x8*)&SH(0, off);
        bf16x8 al = *(bf16x8*)&SH(1, off);
#pragma unroll
        for (int ct = 0; ct < 4; ct++) {
            acc[ct] = __builtin_amdgcn_mfma_f32_16x16x32_bf16(ah, bh[ct], acc[ct], 0, 0, 0);
            acc[ct] = __builtin_amdgcn_mfma_f32_16x16x32_bf16(ah, bl[ct], acc[ct], 0, 0, 0);
            acc[ct] = __builtin_amdgcn_mfma_f32_16x16x32_bf16(al, bh[ct], acc[ct], 0, 0, 0);
        }
    }

    // ---------------- epilogue: +b2 (, ReLU) -> fp32
#pragma unroll
    for (int ct = 0; ct < 4; ct++) {
        int col = wc * 64 + ct * 16 + c;
        float ca2 = b2[col];
#pragma unroll
        for (int r = 0; r < 4; r++) {
            int row = row0 + wr * 16 + g * 4 + r;
            if (row < M) {
                float v = acc[ct][r] + ca2;
                if (RELU_OUT) v = fmaxf(v, 0.f);
                out[(size_t)row * 128 + col] = v;
            }
        }
    }
#undef SH
}

// --------------------------------------------------- pool + final (fused)
// Phase A: node-parallel run-length pool into `pooled` (atomics).
// Software grid barrier (391 blocks x 384 thr = 2346 waves, trivially
// co-resident on 8192-wave device; device-scope atomics).
// Phase B: blocks loop graphs; mean + [384]x[384,128] matvec.
__global__ __launch_bounds__(384) void poolfinal_kernel(
    const float* __restrict__ x1, const float* __restrict__ x2,
    const float* __restrict__ x3, const int* __restrict__ batch,
    float* __restrict__ pooled, const float* __restrict__ W,
    const float* __restrict__ bias, float* __restrict__ out,
    int n, int* __restrict__ bar) {
    __shared__ int bs[128];
    __shared__ float ps[384];
    int b0 = blockIdx.x * 128;
    int t = threadIdx.x;
    int rows = n - b0; if (rows > 128) rows = 128;
    for (int i = t; i < rows; i += 384) bs[i] = batch[b0 + i];
    __syncthreads();
    {
        const float* src = (t < 128) ? x1 : ((t < 256) ? x2 : x3);
        int ch = t & 127;
        int gcur = bs[0];
        float acc = 0.f;
#pragma unroll 8
        for (int r = 0; r < rows; r++) {
            int gg = bs[r];
            if (gg != gcur) {                   // block-uniform branch
                atomicAdd(&pooled[gcur * 384 + t], acc);
                acc = 0.f;
                gcur = gg;
            }
            acc += src[(size_t)(b0 + r) * 128 + ch];
        }
        atomicAdd(&pooled[gcur * 384 + t], acc);
    }
    // ---- software grid barrier
    __threadfence();
    __syncthreads();
    if (t == 0) {
        atomicAdd(bar, 1);
        while (atomicAdd(bar, 0) < (int)gridDim.x) __builtin_amdgcn_s_sleep(8);
    }
    __syncthreads();

    // ---- final: out[g] = mean_pooled[g] @ W + bias
    for (int gph = blockIdx.x; gph < NGRAPHS; gph += gridDim.x) {
        __syncthreads();
        int lo1 = 0, hi1 = n;
        while (lo1 < hi1) { int mid = (lo1 + hi1) >> 1; if (batch[mid] < gph) lo1 = mid + 1; else hi1 = mid; }
        int start = lo1;
        int lo2 = start, hi2 = n;
        while (lo2 < hi2) { int mid = (lo2 + hi2) >> 1; if (batch[mid] < gph + 1) lo2 = mid + 1; else hi2 = mid; }
        int cnt = lo2 - start;
        float inv = 1.f / (float)(cnt > 0 ? cnt : 1);
        // atomics-written data: read with agent-scope atomic loads (bypass L1)
        ps[t] = __hip_atomic_load(&pooled[gph * 384 + t], __ATOMIC_RELAXED,
                                  __HIP_MEMORY_SCOPE_AGENT) * inv;
        __syncthreads();
        if (t < 128) {
            float acc = bias[t];
#pragma unroll 8
            for (int k = 0; k < 384; k++) acc += ps[k] * W[k * 128 + t];
            out[gph * 128 + t] = acc;
        }
    }
}

// ------------------------------------------------------------------ launch
extern "C" void kernel_launch(void* const* d_in, const int* in_sizes, int n_in,
                              void* d_out, int out_size, void* d_ws, size_t ws_size,
                              hipStream_t stream) {
    const float* x     = (const float*)d_in[0];
    const int*   edge  = (const int*)d_in[1];
    const int*   batch = (const int*)d_in[2];
    const float* p[32];
    for (int i = 0; i < n_in && i < 32; i++) p[i] = (const float*)d_in[i];
    const float* lin_W = p[27];
    const float* lin_b = p[28];

    char* w = (char*)d_ws;
    auto alloc = [&](size_t bytes) { void* r = (void*)w; w += (bytes + 255) & ~(size_t)255; return r; };
    const size_t PL = (size_t)NNODES * 128;
    float* x1     = (float*)alloc(PL * 4);
    float* x2b    = (float*)alloc(PL * 4);
    float* x3b    = (float*)alloc(PL * 4);
    float* pooled = (float*)alloc((size_t)NGRAPHS * 384 * 4);
    int* counts   = (int*)alloc((size_t)NNODES * 4);
    int* cursor   = (int*)alloc((size_t)NNODES * 4);
    int* row_ptr  = (int*)alloc((size_t)(NNODES + 1) * 4);
    int* esrc     = (int*)alloc((size_t)NEDGES * 4);
    int* partials = (int*)alloc(256 * 4);
    int* bar      = (int*)alloc(8 * 4);
    ushort* wt_hi = (ushort*)alloc((size_t)6 * 16384 * 2);
    ushort* wt_lo = (ushort*)alloc((size_t)6 * 16384 * 2);

    const int* src = edge;
    const int* dst = edge + NEDGES;

    // --- prep: zero pooled/counts/bar + weight split (1 dispatch)
    prep_kernel<<<485, 256, 0, stream>>>(pooled, counts, bar,
                                         p[3], p[9], p[11], p[17], p[19], p[25],
                                         wt_hi, wt_lo);

    // --- CSR build (reused by all 3 layers)
    hist_kernel<<<(NEDGES + 255) / 256, 256, 0, stream>>>(dst, counts, NEDGES);
    int nb = (NNODES + 255) / 256;  // 196
    scan1_kernel<<<nb, 256, 0, stream>>>(counts, partials, NNODES);
    scan2_kernel<<<1, 256, 0, stream>>>(partials, nb, row_ptr, NEDGES);
    scan3_kernel<<<nb, 256, 0, stream>>>(counts, partials, row_ptr, cursor, NNODES);
    scatter_kernel<<<(NEDGES + 255) / 256, 256, 0, stream>>>(src, dst, cursor, esrc, NEDGES);

    // --- 3 fused GIN layers
    int grid = (NNODES + 31) / 32;   // 1563
    const float* xin = x;
    float* fouts[3] = {x1, x2b, x3b};
    for (int li = 0; li < 3; li++) {
        const float* b1 = p[4 + 8 * li];
        const float* gm = p[5 + 8 * li];
        const float* bt = p[6 + 8 * li];
        const float* rm = p[7 + 8 * li];
        const float* rv = p[8 + 8 * li];
        const float* b2 = p[10 + 8 * li];
        const ushort* w1h = wt_hi + (size_t)(2 * li) * 16384;
        const ushort* w1l = wt_lo + (size_t)(2 * li) * 16384;
        const ushort* w2h = wt_hi + (size_t)(2 * li + 1) * 16384;
        const ushort* w2l = wt_lo + (size_t)(2 * li + 1) * 16384;

        if (li < 2)
            layer_kernel<true><<<grid, 256, 0, stream>>>(xin, row_ptr, esrc,
                                                         w1h, w1l, w2h, w2l,
                                                         b1, gm, bt, rm, rv, b2,
                                                         fouts[li], NNODES);
        else
            layer_kernel<false><<<grid, 256, 0, stream>>>(xin, row_ptr, esrc,
                                                          w1h, w1l, w2h, w2l,
                                                          b1, gm, bt, rm, rv, b2,
                                                          fouts[li], NNODES);
        xin = fouts[li];
    }

    // --- JK-concat mean pool + final linear (one kernel, software barrier)
    poolfinal_kernel<<<(NNODES + 127) / 128, 384, 0, stream>>>(
        x1, x2b, x3b, batch, pooled, lin_W, lin_b, (float*)d_out, NNODES, bar);
}

// Round 8
// 583.567 us; speedup vs baseline: 1.1220x; 1.1220x over previous
//
#include <hip/hip_runtime.h>
#include <hip/hip_bf16.h>

#define NNODES 50000
#define NEDGES 600000
#define NGRAPHS 512
#define BN_EPS 1e-5f

typedef short bf16x8 __attribute__((ext_vector_type(8)));
typedef float f32x4 __attribute__((ext_vector_type(4)));

// split fp32 -> hi/lo bf16 (RNE); hi+lo carries ~16 mantissa bits
__device__ __forceinline__ void bf_split(float x, ushort& h, ushort& l) {
    __hip_bfloat16 bh = __float2bfloat16(x);
    float r = x - __bfloat162float(bh);
    __hip_bfloat16 bl = __float2bfloat16(r);
    h = __builtin_bit_cast(ushort, bh);
    l = __builtin_bit_cast(ushort, bl);
}

// ------------------------------------------------------------------- prep
// One kernel (no barriers): zero pooled (blocks 0..191), zero counts
// (192..387), wsplit 6 matrices (388..483).
__global__ __launch_bounds__(256) void prep_kernel(
    float* __restrict__ pooled, int* __restrict__ counts,
    const float* W0, const float* W1, const float* W2, const float* W3,
    const float* W4, const float* W5, ushort* __restrict__ hi, ushort* __restrict__ lo) {
    int b = blockIdx.x, t = threadIdx.x;
    if (b < 192) {                                  // pooled: 512*384 floats
        ((float4*)pooled)[b * 256 + t] = make_float4(0.f, 0.f, 0.f, 0.f);
    } else if (b < 388) {                           // counts: 50000 ints
        int i = (b - 192) * 256 + t;
        if (i < NNODES) counts[i] = 0;
    } else {                                        // wsplit: 96 blocks
        int wb = b - 388;
        const float* Ws[6] = {W0, W1, W2, W3, W4, W5};
        const float* W = Ws[wb >> 4];
        ushort* h = hi + (size_t)(wb >> 4) * 16384;
        ushort* l = lo + (size_t)(wb >> 4) * 16384;
        int chunk = wb & 15;
#pragma unroll
        for (int i = 0; i < 4; i++) {
            int idx = chunk * 1024 + i * 256 + t;
            int n = idx >> 7, k = idx & 127;
            ushort hh, ll;
            bf_split(W[k * 128 + n], hh, ll);
            h[n * 128 + k] = hh;
            l[n * 128 + k] = ll;
        }
    }
}

// ---------------------------------------------------------------- CSR build
__global__ __launch_bounds__(256) void hist_kernel(const int* __restrict__ dst,
                                                   int* __restrict__ counts, int E) {
    int i = blockIdx.x * 256 + threadIdx.x;
    if (i < E) atomicAdd(&counts[dst[i]], 1);
}

__global__ __launch_bounds__(256) void scan1_kernel(const int* __restrict__ counts,
                                                    int* __restrict__ partials, int n) {
    __shared__ int s[256];
    int i = blockIdx.x * 256 + threadIdx.x;
    int v = (i < n) ? counts[i] : 0;
    s[threadIdx.x] = v;
    __syncthreads();
    for (int off = 128; off > 0; off >>= 1) {
        if (threadIdx.x < off) s[threadIdx.x] += s[threadIdx.x + off];
        __syncthreads();
    }
    if (threadIdx.x == 0) partials[blockIdx.x] = s[0];
}

__global__ __launch_bounds__(256) void scan2_kernel(int* __restrict__ partials, int nb,
                                                    int* __restrict__ row_ptr, int total) {
    __shared__ int s[256];
    int t = threadIdx.x;
    int v = (t < nb) ? partials[t] : 0;
    s[t] = v;
    __syncthreads();
    for (int off = 1; off < 256; off <<= 1) {
        int nv = (t >= off) ? s[t - off] : 0;
        __syncthreads();
        s[t] += nv;
        __syncthreads();
    }
    if (t < nb) partials[t] = s[t] - v;   // exclusive
    if (t == 0) row_ptr[NNODES] = total;
}

__global__ __launch_bounds__(256) void scan3_kernel(const int* __restrict__ counts,
                                                    const int* __restrict__ partials,
                                                    int* __restrict__ row_ptr,
                                                    int* __restrict__ cursor, int n) {
    __shared__ int s[256];
    int i = blockIdx.x * 256 + threadIdx.x;
    int v = (i < n) ? counts[i] : 0;
    s[threadIdx.x] = v;
    __syncthreads();
    for (int off = 1; off < 256; off <<= 1) {
        int nv = (threadIdx.x >= (unsigned)off) ? s[threadIdx.x - off] : 0;
        __syncthreads();
        s[threadIdx.x] += nv;
        __syncthreads();
    }
    if (i < n) {
        int ex = partials[blockIdx.x] + s[threadIdx.x] - v;  // exclusive
        row_ptr[i] = ex;
        cursor[i] = ex;
    }
}

__global__ __launch_bounds__(256) void scatter_kernel(const int* __restrict__ src,
                                                      const int* __restrict__ dst,
                                                      int* __restrict__ cursor,
                                                      int* __restrict__ esrc, int E) {
    int i = blockIdx.x * 256 + threadIdx.x;
    if (i < E) {
        int p = atomicAdd(&cursor[dst[i]], 1);
        esrc[p] = src[i];
    }
}

// ------------------------------------------------------------ fused layer
// out = act( BN_ReLU( (x + sum_nbr x) @ W1 ) @ W2 + b2 ), 64 nodes/block,
// 512 threads (8 waves). R6 (256 thr) measured: 82us, hbm 2.06 TB/s,
// gather-bound at ~96 outstanding loads/CU. This version doubles gather
// waves (24/CU at 3 blocks/CU) + unroll-8 -> ~300 outstanding, targeting
// agg-standalone's 3.7 TB/s. MFMA: 8 waves x (16 rows x 64 cols) wave-tile
// = 1x4 of 16x16x32; acc = 16 VGPR/wave (no occupancy cliff).
// LDS 34.8KB: A hi/lo planes (stride 136: 16B-aligned b128, balanced banks),
// reused for H planes after phase 1. 3 barriers total.
#define HSTR 136
#define PPLANE (64 * HSTR)       // 8704
template <bool RELU_OUT>
__global__ __launch_bounds__(512) void layer_kernel(
    const float* __restrict__ xin, const int* __restrict__ rp,
    const int* __restrict__ esrc,
    const ushort* __restrict__ W1hi, const ushort* __restrict__ W1lo,
    const ushort* __restrict__ W2hi, const ushort* __restrict__ W2lo,
    const float* __restrict__ b1, const float* __restrict__ gm,
    const float* __restrict__ bt, const float* __restrict__ rm,
    const float* __restrict__ rv, const float* __restrict__ b2,
    float* __restrict__ out, int M) {
    __shared__ __align__(16) ushort smem[2 * PPLANE];   // 34816 B
#define SH(p_, o_) smem[(p_)*PPLANE + (o_)]
    const int t = threadIdx.x;
    const int lane = t & 63;
    const int wv = t >> 6;                   // 0..7
    const int wr = wv >> 1, wc = wv & 1;     // 4 row-groups x 2 col-halves
    const int row0 = blockIdx.x * 64;
    const int g = lane >> 4, c = lane & 15;
    const int q = lane & 31;

    // ---------------- phase 0: gather + split into LDS A planes
    // 8 waves x 4 passes x 2 nodes = 64 nodes; unroll-8 = 8 float4/node in flight
    const float4* x4 = (const float4*)xin;
#pragma unroll 1
    for (int pass = 0; pass < 4; pass++) {
        int nt = wv * 8 + pass * 2 + (lane >> 5);
        int node = row0 + nt;
        float4 acc = make_float4(0.f, 0.f, 0.f, 0.f);
        if (node < M) {
            acc = x4[(size_t)node * 32 + q];   // self term (eps=0)
            int beg = rp[node], end = rp[node + 1];
            int e = beg;
            for (; e + 8 <= end; e += 8) {
                int i0 = esrc[e],     i1 = esrc[e + 1], i2 = esrc[e + 2], i3 = esrc[e + 3];
                int i4 = esrc[e + 4], i5 = esrc[e + 5], i6 = esrc[e + 6], i7 = esrc[e + 7];
                float4 v0 = x4[(size_t)i0 * 32 + q];
                float4 v1 = x4[(size_t)i1 * 32 + q];
                float4 v2 = x4[(size_t)i2 * 32 + q];
                float4 v3 = x4[(size_t)i3 * 32 + q];
                float4 v4 = x4[(size_t)i4 * 32 + q];
                float4 v5 = x4[(size_t)i5 * 32 + q];
                float4 v6 = x4[(size_t)i6 * 32 + q];
                float4 v7 = x4[(size_t)i7 * 32 + q];
                acc.x += ((v0.x + v1.x) + (v2.x + v3.x)) + ((v4.x + v5.x) + (v6.x + v7.x));
                acc.y += ((v0.y + v1.y) + (v2.y + v3.y)) + ((v4.y + v5.y) + (v6.y + v7.y));
                acc.z += ((v0.z + v1.z) + (v2.z + v3.z)) + ((v4.z + v5.z) + (v6.z + v7.z));
                acc.w += ((v0.w + v1.w) + (v2.w + v3.w)) + ((v4.w + v5.w) + (v6.w + v7.w));
            }
            for (; e + 2 <= end; e += 2) {
                int i0 = esrc[e], i1 = esrc[e + 1];
                float4 v0 = x4[(size_t)i0 * 32 + q];
                float4 v1 = x4[(size_t)i1 * 32 + q];
                acc.x += v0.x + v1.x; acc.y += v0.y + v1.y;
                acc.z += v0.z + v1.z; acc.w += v0.w + v1.w;
            }
            for (; e < end; e++) {
                int i0 = esrc[e];
                float4 v = x4[(size_t)i0 * 32 + q];
                acc.x += v.x; acc.y += v.y; acc.z += v.z; acc.w += v.w;
            }
        }
        ushort4 hh, ll;
        bf_split(acc.x, hh.x, ll.x);
        bf_split(acc.y, hh.y, ll.y);
        bf_split(acc.z, hh.z, ll.z);
        bf_split(acc.w, hh.w, ll.w);
        *(ushort4*)&SH(0, nt * HSTR + q * 4) = hh;
        *(ushort4*)&SH(1, nt * HSTR + q * 4) = ll;
    }
    __syncthreads();

    // ---------------- phase 1: A @ W1 (W frags direct from global, L2-hot)
    f32x4 acc[4];
#pragma unroll
    for (int j = 0; j < 4; j++) acc[j] = (f32x4){0.f, 0.f, 0.f, 0.f};

#pragma unroll
    for (int kb = 0; kb < 4; kb++) {
        bf16x8 bh[4], bl[4];
#pragma unroll
        for (int ct = 0; ct < 4; ct++) {
            const size_t wo = (size_t)(wc * 64 + ct * 16 + c) * 128 + kb * 32 + g * 8;
            bh[ct] = *(const bf16x8*)(W1hi + wo);
            bl[ct] = *(const bf16x8*)(W1lo + wo);
        }
        int off = (wr * 16 + c) * HSTR + kb * 32 + g * 8;
        bf16x8 ah = *(bf16x8*)&SH(0, off);
        bf16x8 al = *(bf16x8*)&SH(1, off);
#pragma unroll
        for (int ct = 0; ct < 4; ct++) {
            acc[ct] = __builtin_amdgcn_mfma_f32_16x16x32_bf16(ah, bh[ct], acc[ct], 0, 0, 0);
            acc[ct] = __builtin_amdgcn_mfma_f32_16x16x32_bf16(ah, bl[ct], acc[ct], 0, 0, 0);
            acc[ct] = __builtin_amdgcn_mfma_f32_16x16x32_bf16(al, bh[ct], acc[ct], 0, 0, 0);
        }
    }
    __syncthreads();   // all A reads done -> H may overwrite

    // ---------------- BN + ReLU -> H planes (same LDS)
    {
#pragma unroll
        for (int ct = 0; ct < 4; ct++) {
            int n = wc * 64 + ct * 16 + c;
            float s = gm[n] * rsqrtf(rv[n] + BN_EPS);
            float ca = (b1[n] - rm[n]) * s + bt[n];
#pragma unroll
            for (int r = 0; r < 4; r++) {
                int row = wr * 16 + g * 4 + r;
                float v = fmaxf(acc[ct][r] * s + ca, 0.f);
                ushort hh, ll;
                bf_split(v, hh, ll);
                SH(0, row * HSTR + n) = hh;
                SH(1, row * HSTR + n) = ll;
            }
        }
    }
    __syncthreads();

    // ---------------- phase 2: H @ W2
#pragma unroll
    for (int j = 0; j < 4; j++) acc[j] = (f32x4){0.f, 0.f, 0.f, 0.f};

#pragma unroll
    for (int kb = 0; kb < 4; kb++) {
        bf16x8 bh[4], bl[4];
#pragma unroll
        for (int ct = 0; ct < 4; ct++) {
            const size_t wo = (size_t)(wc * 64 + ct * 16 + c) * 128 + kb * 32 + g * 8;
            bh[ct] = *(const bf16x8*)(W2hi + wo);
            bl[ct] = *(const bf16x8*)(W2lo + wo);
        }
        int off = (wr * 16 + c) * HSTR + kb * 32 + g * 8;
        bf16x8 ah = *(bf16x8*)&SH(0, off);
        bf16x8 al = *(bf16x8*)&SH(1, off);
#pragma unroll
        for (int ct = 0; ct < 4; ct++) {
            acc[ct] = __builtin_amdgcn_mfma_f32_16x16x32_bf16(ah, bh[ct], acc[ct], 0, 0, 0);
            acc[ct] = __builtin_amdgcn_mfma_f32_16x16x32_bf16(ah, bl[ct], acc[ct], 0, 0, 0);
            acc[ct] = __builtin_amdgcn_mfma_f32_16x16x32_bf16(al, bh[ct], acc[ct], 0, 0, 0);
        }
    }

    // ---------------- epilogue: +b2 (, ReLU) -> fp32
#pragma unroll
    for (int ct = 0; ct < 4; ct++) {
        int col = wc * 64 + ct * 16 + c;
        float ca2 = b2[col];
#pragma unroll
        for (int r = 0; r < 4; r++) {
            int row = row0 + wr * 16 + g * 4 + r;
            if (row < M) {
                float v = acc[ct][r] + ca2;
                if (RELU_OUT) v = fmaxf(v, 0.f);
                out[(size_t)row * 128 + col] = v;
            }
        }
    }
#undef SH
}

// ----------------------------------------------------------------- pooling
__global__ __launch_bounds__(384) void pool_kernel(const float* __restrict__ x1,
                                                   const float* __restrict__ x2,
                                                   const float* __restrict__ x3,
                                                   const int* __restrict__ batch,
                                                   float* __restrict__ pooled, int n) {
    __shared__ int bs[128];
    int b0 = blockIdx.x * 128;
    int t = threadIdx.x;
    int rows = n - b0; if (rows > 128) rows = 128;
    for (int i = t; i < rows; i += 384) bs[i] = batch[b0 + i];
    __syncthreads();
    const float* src = (t < 128) ? x1 : ((t < 256) ? x2 : x3);
    int ch = t & 127;
    int gcur = bs[0];
    float acc = 0.f;
#pragma unroll 8
    for (int r = 0; r < rows; r++) {
        int gg = bs[r];
        if (gg != gcur) {                       // block-uniform branch
            atomicAdd(&pooled[gcur * 384 + t], acc);
            acc = 0.f;
            gcur = gg;
        }
        acc += src[(size_t)(b0 + r) * 128 + ch];
    }
    atomicAdd(&pooled[gcur * 384 + t], acc);
}

__global__ __launch_bounds__(128) void final_kernel(const float* __restrict__ pooled,
                                                    const int* __restrict__ batch,
                                                    const float* __restrict__ W,
                                                    const float* __restrict__ b,
                                                    float* __restrict__ out, int n) {
    __shared__ float ps[384];
    int gph = blockIdx.x, t = threadIdx.x;
    int lo1 = 0, hi1 = n;
    while (lo1 < hi1) { int mid = (lo1 + hi1) >> 1; if (batch[mid] < gph) lo1 = mid + 1; else hi1 = mid; }
    int start = lo1;
    int lo2 = start, hi2 = n;
    while (lo2 < hi2) { int mid = (lo2 + hi2) >> 1; if (batch[mid] < gph + 1) lo2 = mid + 1; else hi2 = mid; }
    int cnt = lo2 - start;
    float inv = 1.f / (float)(cnt > 0 ? cnt : 1);
    for (int i = t; i < 384; i += 128) ps[i] = pooled[gph * 384 + i] * inv;
    __syncthreads();
    float acc = b[t];
#pragma unroll 8
    for (int k = 0; k < 384; k++) acc += ps[k] * W[k * 128 + t];
    out[gph * 128 + t] = acc;
}

// ------------------------------------------------------------------ launch
extern "C" void kernel_launch(void* const* d_in, const int* in_sizes, int n_in,
                              void* d_out, int out_size, void* d_ws, size_t ws_size,
                              hipStream_t stream) {
    const float* x     = (const float*)d_in[0];
    const int*   edge  = (const int*)d_in[1];
    const int*   batch = (const int*)d_in[2];
    const float* p[32];
    for (int i = 0; i < n_in && i < 32; i++) p[i] = (const float*)d_in[i];
    const float* lin_W = p[27];
    const float* lin_b = p[28];

    char* w = (char*)d_ws;
    auto alloc = [&](size_t bytes) { void* r = (void*)w; w += (bytes + 255) & ~(size_t)255; return r; };
    const size_t PL = (size_t)NNODES * 128;
    float* x1     = (float*)alloc(PL * 4);
    float* x2b    = (float*)alloc(PL * 4);
    float* x3b    = (float*)alloc(PL * 4);
    float* pooled = (float*)alloc((size_t)NGRAPHS * 384 * 4);
    int* counts   = (int*)alloc((size_t)NNODES * 4);
    int* cursor   = (int*)alloc((size_t)NNODES * 4);
    int* row_ptr  = (int*)alloc((size_t)(NNODES + 1) * 4);
    int* esrc     = (int*)alloc((size_t)NEDGES * 4);
    int* partials = (int*)alloc(256 * 4);
    ushort* wt_hi = (ushort*)alloc((size_t)6 * 16384 * 2);
    ushort* wt_lo = (ushort*)alloc((size_t)6 * 16384 * 2);

    const int* src = edge;
    const int* dst = edge + NEDGES;

    // --- prep: zero pooled/counts + weight split (1 dispatch, no barriers)
    prep_kernel<<<484, 256, 0, stream>>>(pooled, counts,
                                         p[3], p[9], p[11], p[17], p[19], p[25],
                                         wt_hi, wt_lo);

    // --- CSR build (reused by all 3 layers)
    hist_kernel<<<(NEDGES + 255) / 256, 256, 0, stream>>>(dst, counts, NEDGES);
    int nb = (NNODES + 255) / 256;  // 196
    scan1_kernel<<<nb, 256, 0, stream>>>(counts, partials, NNODES);
    scan2_kernel<<<1, 256, 0, stream>>>(partials, nb, row_ptr, NEDGES);
    scan3_kernel<<<nb, 256, 0, stream>>>(counts, partials, row_ptr, cursor, NNODES);
    scatter_kernel<<<(NEDGES + 255) / 256, 256, 0, stream>>>(src, dst, cursor, esrc, NEDGES);

    // --- 3 fused GIN layers (512 threads: 8 gather waves/block)
    int grid = (NNODES + 63) / 64;   // 782
    const float* xin = x;
    float* fouts[3] = {x1, x2b, x3b};
    for (int li = 0; li < 3; li++) {
        const float* b1 = p[4 + 8 * li];
        const float* gm = p[5 + 8 * li];
        const float* bt = p[6 + 8 * li];
        const float* rm = p[7 + 8 * li];
        const float* rv = p[8 + 8 * li];
        const float* b2 = p[10 + 8 * li];
        const ushort* w1h = wt_hi + (size_t)(2 * li) * 16384;
        const ushort* w1l = wt_lo + (size_t)(2 * li) * 16384;
        const ushort* w2h = wt_hi + (size_t)(2 * li + 1) * 16384;
        const ushort* w2l = wt_lo + (size_t)(2 * li + 1) * 16384;

        if (li < 2)
            layer_kernel<true><<<grid, 512, 0, stream>>>(xin, row_ptr, esrc,
                                                         w1h, w1l, w2h, w2l,
                                                         b1, gm, bt, rm, rv, b2,
                                                         fouts[li], NNODES);
        else
            layer_kernel<false><<<grid, 512, 0, stream>>>(xin, row_ptr, esrc,
                                                          w1h, w1l, w2h, w2l,
                                                          b1, gm, bt, rm, rv, b2,
                                                          fouts[li], NNODES);
        xin = fouts[li];
    }

    // --- JK-concat mean pool + final linear (separate, known-good)
    pool_kernel<<<(NNODES + 127) / 128, 384, 0, stream>>>(x1, x2b, x3b, batch, pooled, NNODES);
    final_kernel<<<NGRAPHS, 128, 0, stream>>>(pooled, batch, lin_W, lin_b, (float*)d_out, NNODES);
}

// Round 9
// 454.155 us; speedup vs baseline: 1.4417x; 1.2850x over previous
//
#include <hip/hip_runtime.h>
#include <hip/hip_bf16.h>

#define NNODES 50000
#define NEDGES 600000
#define NGRAPHS 512
#define BN_EPS 1e-5f

typedef short bf16x8 __attribute__((ext_vector_type(8)));
typedef float f32x4 __attribute__((ext_vector_type(4)));

// split fp32 -> hi/lo bf16 (RNE); hi+lo carries ~16 mantissa bits
__device__ __forceinline__ void bf_split(float x, ushort& h, ushort& l) {
    __hip_bfloat16 bh = __float2bfloat16(x);
    float r = x - __bfloat162float(bh);
    __hip_bfloat16 bl = __float2bfloat16(r);
    h = __builtin_bit_cast(ushort, bh);
    l = __builtin_bit_cast(ushort, bl);
}

// ------------------------------------------------------------------- prep
// One dispatch, no barriers: zero pooled (blocks 0..191), zero counts
// (192..387), wsplit 6 matrices (388..483), row_ptr[N] init (block 0).
__global__ __launch_bounds__(256) void prep_kernel(
    float* __restrict__ pooled, int* __restrict__ counts, int* __restrict__ row_ptr,
    const float* W0, const float* W1, const float* W2, const float* W3,
    const float* W4, const float* W5, ushort* __restrict__ hi, ushort* __restrict__ lo) {
    int b = blockIdx.x, t = threadIdx.x;
    if (b < 192) {                                  // pooled: 512*384 floats
        ((float4*)pooled)[b * 256 + t] = make_float4(0.f, 0.f, 0.f, 0.f);
        if (b == 0 && t == 0) row_ptr[NNODES] = NEDGES;
    } else if (b < 388) {                           // counts: 50000 ints
        int i = (b - 192) * 256 + t;
        if (i < NNODES) counts[i] = 0;
    } else {                                        // wsplit: 96 blocks
        int wb = b - 388;
        const float* Ws[6] = {W0, W1, W2, W3, W4, W5};
        const float* W = Ws[wb >> 4];
        ushort* h = hi + (size_t)(wb >> 4) * 16384;
        ushort* l = lo + (size_t)(wb >> 4) * 16384;
        int chunk = wb & 15;
#pragma unroll
        for (int i = 0; i < 4; i++) {
            int idx = chunk * 1024 + i * 256 + t;
            int n = idx >> 7, k = idx & 127;
            ushort hh, ll;
            bf_split(W[k * 128 + n], hh, ll);
            h[n * 128 + k] = hh;
            l[n * 128 + k] = ll;
        }
    }
}

// ---------------------------------------------------------------- CSR build
__global__ __launch_bounds__(256) void hist_kernel(const int* __restrict__ dst,
                                                   int* __restrict__ counts, int E) {
    int i = blockIdx.x * 256 + threadIdx.x;
    if (i < E) atomicAdd(&counts[dst[i]], 1);
}

__global__ __launch_bounds__(256) void scan1_kernel(const int* __restrict__ counts,
                                                    int* __restrict__ partials, int n) {
    __shared__ int s[256];
    int i = blockIdx.x * 256 + threadIdx.x;
    int v = (i < n) ? counts[i] : 0;
    s[threadIdx.x] = v;
    __syncthreads();
    for (int off = 128; off > 0; off >>= 1) {
        if (threadIdx.x < off) s[threadIdx.x] += s[threadIdx.x + off];
        __syncthreads();
    }
    if (threadIdx.x == 0) partials[blockIdx.x] = s[0];
}

// scan3 with inline base computation (replaces the old scan2 dispatch):
// each block reduces partials[i < blockIdx.x] itself (nb<=256).
__global__ __launch_bounds__(256) void scan3_kernel(const int* __restrict__ counts,
                                                    const int* __restrict__ partials,
                                                    int* __restrict__ row_ptr,
                                                    int* __restrict__ cursor, int n, int nb) {
    __shared__ int s[256];
    __shared__ int base_sh;
    int t = threadIdx.x;
    int pv = (t < (int)blockIdx.x && t < nb) ? partials[t] : 0;
    s[t] = pv;
    __syncthreads();
    for (int off = 128; off > 0; off >>= 1) {
        if (t < off) s[t] += s[t + off];
        __syncthreads();
    }
    if (t == 0) base_sh = s[0];
    __syncthreads();
    int base = base_sh;
    int i = blockIdx.x * 256 + t;
    int v = (i < n) ? counts[i] : 0;
    __syncthreads();
    s[t] = v;
    __syncthreads();
    for (int off = 1; off < 256; off <<= 1) {
        int nv = (t >= off) ? s[t - off] : 0;
        __syncthreads();
        s[t] += nv;
        __syncthreads();
    }
    if (i < n) {
        int ex = base + s[t] - v;   // exclusive
        row_ptr[i] = ex;
        cursor[i] = ex;
    }
}

__global__ __launch_bounds__(256) void scatter_kernel(const int* __restrict__ src,
                                                      const int* __restrict__ dst,
                                                      int* __restrict__ cursor,
                                                      int* __restrict__ esrc, int E) {
    int i = blockIdx.x * 256 + threadIdx.x;
    if (i < E) {
        int p = atomicAdd(&cursor[dst[i]], 1);
        esrc[p] = src[i];
    }
}

// ------------------------------------------------------------- aggregation
// (R5-proven: 47us, ~3.7 TB/s fabric ceiling, barrier-free 6250 blocks)
// 2 nodes/wave, 32 lanes x float4; exact fp32 sum -> pre-split hi/lo planes.
__global__ __launch_bounds__(256) void agg_kernel(const float* __restrict__ x,
                                                  const int* __restrict__ rp,
                                                  const int* __restrict__ esrc,
                                                  ushort* __restrict__ ohi,
                                                  ushort* __restrict__ olo, int n) {
    int wid  = (blockIdx.x * 256 + threadIdx.x) >> 6;
    int lane = threadIdx.x & 63;
    int node = wid * 2 + (lane >> 5);
    int q = lane & 31;
    if (node >= n) return;
    const float4* x4 = (const float4*)x;
    float4 acc = x4[(size_t)node * 32 + q];   // self term (eps=0)
    int beg = rp[node], end = rp[node + 1];
    int e = beg;
    for (; e + 8 <= end; e += 8) {
        int i0 = esrc[e],     i1 = esrc[e + 1], i2 = esrc[e + 2], i3 = esrc[e + 3];
        int i4 = esrc[e + 4], i5 = esrc[e + 5], i6 = esrc[e + 6], i7 = esrc[e + 7];
        float4 v0 = x4[(size_t)i0 * 32 + q];
        float4 v1 = x4[(size_t)i1 * 32 + q];
        float4 v2 = x4[(size_t)i2 * 32 + q];
        float4 v3 = x4[(size_t)i3 * 32 + q];
        float4 v4 = x4[(size_t)i4 * 32 + q];
        float4 v5 = x4[(size_t)i5 * 32 + q];
        float4 v6 = x4[(size_t)i6 * 32 + q];
        float4 v7 = x4[(size_t)i7 * 32 + q];
        acc.x += ((v0.x + v1.x) + (v2.x + v3.x)) + ((v4.x + v5.x) + (v6.x + v7.x));
        acc.y += ((v0.y + v1.y) + (v2.y + v3.y)) + ((v4.y + v5.y) + (v6.y + v7.y));
        acc.z += ((v0.z + v1.z) + (v2.z + v3.z)) + ((v4.z + v5.z) + (v6.z + v7.z));
        acc.w += ((v0.w + v1.w) + (v2.w + v3.w)) + ((v4.w + v5.w) + (v6.w + v7.w));
    }
    for (; e + 2 <= end; e += 2) {
        int i0 = esrc[e], i1 = esrc[e + 1];
        float4 v0 = x4[(size_t)i0 * 32 + q];
        float4 v1 = x4[(size_t)i1 * 32 + q];
        acc.x += v0.x + v1.x; acc.y += v0.y + v1.y;
        acc.z += v0.z + v1.z; acc.w += v0.w + v1.w;
    }
    for (; e < end; e++) {
        int i0 = esrc[e];
        float4 v = x4[(size_t)i0 * 32 + q];
        acc.x += v.x; acc.y += v.y; acc.z += v.z; acc.w += v.w;
    }
    ushort4 hh, ll;
    bf_split(acc.x, hh.x, ll.x);
    bf_split(acc.y, hh.y, ll.y);
    bf_split(acc.z, hh.z, ll.z);
    bf_split(acc.w, hh.w, ll.w);
    *(ushort4*)(ohi + (size_t)node * 128 + q * 4) = hh;
    *(ushort4*)(olo + (size_t)node * 128 + q * 4) = ll;
}

// --------------------------------------------------------------- fused MLP
// (R5-proven: ~27us/dispatch) C = act( BN_ReLU( A@W1 ) @ W2 ), 128-row tile,
// split-bf16 MFMA (hi@hi + hi@lo + lo@hi). A planes dbuf in LDS; W frags
// direct from global (L2-hot). H lives in LDS (pad 136). LDS 68KB.
#define HP 136
template <bool RELU_OUT>
__global__ __launch_bounds__(256) void mlp_kernel(
    const ushort* __restrict__ Ahi, const ushort* __restrict__ Alo,
    const ushort* __restrict__ W1hi, const ushort* __restrict__ W1lo,
    const ushort* __restrict__ W2hi, const ushort* __restrict__ W2lo,
    const float* __restrict__ b1, const float* __restrict__ gm,
    const float* __restrict__ bt, const float* __restrict__ rm,
    const float* __restrict__ rv, const float* __restrict__ b2,
    float* __restrict__ C, int M) {
    __shared__ __align__(16) ushort smem[2 * 128 * HP];   // 69632 B
#define AS(b_, p_, o_) smem[(((b_) * 2 + (p_)) << 12) + (o_)]
#define HS(p_, o_) smem[(p_)*128 * HP + (o_)]
    const int t = threadIdx.x;
    const int lane = t & 63;
    const int wv = t >> 6;
    const int wr = wv >> 1, wc = wv & 1;
    const int row0 = blockIdx.x * 128;
    const int g = lane >> 4, c = lane & 15;

    const int m0 = t >> 2,  k80 = (t & 3) * 8;
    const int m1 = m0 + 64;
    int r0 = row0 + m0; if (r0 >= M) r0 = M - 1;
    int r1 = row0 + m1; if (r1 >= M) r1 = M - 1;
    const size_t ga0 = (size_t)r0 * 128 + k80;
    const size_t ga1 = (size_t)r1 * 128 + k80;
    const int la0 = m0 * 32 + k80, la1 = m1 * 32 + k80;

    f32x4 acc[4][4];
#pragma unroll
    for (int i = 0; i < 4; i++)
#pragma unroll
        for (int j = 0; j < 4; j++) acc[i][j] = (f32x4){0.f, 0.f, 0.f, 0.f};

    uint4 ph0 = *(const uint4*)(Ahi + ga0);
    uint4 ph1 = *(const uint4*)(Ahi + ga1);
    uint4 pl0 = *(const uint4*)(Alo + ga0);
    uint4 pl1 = *(const uint4*)(Alo + ga1);
    *(uint4*)&AS(0, 0, la0) = ph0;
    *(uint4*)&AS(0, 0, la1) = ph1;
    *(uint4*)&AS(0, 1, la0) = pl0;
    *(uint4*)&AS(0, 1, la1) = pl1;
    __syncthreads();

    // ---------------- phase 1: A @ W1
    int cur = 0;
    for (int kb = 0; kb < 4; kb++) {
        bf16x8 bh[4], bl[4];
#pragma unroll
        for (int ct = 0; ct < 4; ct++) {
            const size_t wo = (size_t)(wc * 64 + ct * 16 + c) * 128 + kb * 32 + g * 8;
            bh[ct] = *(const bf16x8*)(W1hi + wo);
            bl[ct] = *(const bf16x8*)(W1lo + wo);
        }
        if (kb < 3) {
            const size_t o = (size_t)(kb + 1) * 32;
            ph0 = *(const uint4*)(Ahi + ga0 + o);
            ph1 = *(const uint4*)(Ahi + ga1 + o);
            pl0 = *(const uint4*)(Alo + ga0 + o);
            pl1 = *(const uint4*)(Alo + ga1 + o);
        }
        bf16x8 ah[4], al[4];
#pragma unroll
        for (int rt = 0; rt < 4; rt++) {
            int off = (wr * 64 + rt * 16 + c) * 32 + g * 8;
            ah[rt] = *(bf16x8*)&AS(cur, 0, off);
            al[rt] = *(bf16x8*)&AS(cur, 1, off);
        }
#pragma unroll
        for (int rt = 0; rt < 4; rt++)
#pragma unroll
            for (int ct = 0; ct < 4; ct++) {
                acc[rt][ct] = __builtin_amdgcn_mfma_f32_16x16x32_bf16(ah[rt], bh[ct], acc[rt][ct], 0, 0, 0);
                acc[rt][ct] = __builtin_amdgcn_mfma_f32_16x16x32_bf16(ah[rt], bl[ct], acc[rt][ct], 0, 0, 0);
                acc[rt][ct] = __builtin_amdgcn_mfma_f32_16x16x32_bf16(al[rt], bh[ct], acc[rt][ct], 0, 0, 0);
            }
        if (kb < 3) {
            *(uint4*)&AS(cur ^ 1, 0, la0) = ph0;
            *(uint4*)&AS(cur ^ 1, 0, la1) = ph1;
            *(uint4*)&AS(cur ^ 1, 1, la0) = pl0;
            *(uint4*)&AS(cur ^ 1, 1, la1) = pl1;
        }
        __syncthreads();   // final iter: all As reads done -> H may alias
        cur ^= 1;
    }

    // ---------------- BN + ReLU -> H (hi/lo bf16) in LDS
    {
        float cs[4], ca[4];
#pragma unroll
        for (int ct = 0; ct < 4; ct++) {
            int n = wc * 64 + ct * 16 + c;
            float s = gm[n] * rsqrtf(rv[n] + BN_EPS);
            cs[ct] = s;
            ca[ct] = (b1[n] - rm[n]) * s + bt[n];
        }
#pragma unroll
        for (int rt = 0; rt < 4; rt++)
#pragma unroll
            for (int r = 0; r < 4; r++) {
                int row = wr * 64 + rt * 16 + g * 4 + r;
#pragma unroll
                for (int ct = 0; ct < 4; ct++) {
                    int col = wc * 64 + ct * 16 + c;
                    float v = fmaxf(acc[rt][ct][r] * cs[ct] + ca[ct], 0.f);
                    ushort hh, ll;
                    bf_split(v, hh, ll);
                    HS(0, row * HP + col) = hh;
                    HS(1, row * HP + col) = ll;
                }
            }
    }
    __syncthreads();

    // ---------------- phase 2: H @ W2
#pragma unroll
    for (int i = 0; i < 4; i++)
#pragma unroll
        for (int j = 0; j < 4; j++) acc[i][j] = (f32x4){0.f, 0.f, 0.f, 0.f};

    for (int kb = 0; kb < 4; kb++) {
        bf16x8 bh[4], bl[4];
#pragma unroll
        for (int ct = 0; ct < 4; ct++) {
            const size_t wo = (size_t)(wc * 64 + ct * 16 + c) * 128 + kb * 32 + g * 8;
            bh[ct] = *(const bf16x8*)(W2hi + wo);
            bl[ct] = *(const bf16x8*)(W2lo + wo);
        }
        bf16x8 ah[4], al[4];
#pragma unroll
        for (int rt = 0; rt < 4; rt++) {
            int off = (wr * 64 + rt * 16 + c) * HP + kb * 32 + g * 8;
            ah[rt] = *(bf16x8*)&HS(0, off);
            al[rt] = *(bf16x8*)&HS(1, off);
        }
#pragma unroll
        for (int rt = 0; rt < 4; rt++)
#pragma unroll
            for (int ct = 0; ct < 4; ct++) {
                acc[rt][ct] = __builtin_amdgcn_mfma_f32_16x16x32_bf16(ah[rt], bh[ct], acc[rt][ct], 0, 0, 0);
                acc[rt][ct] = __builtin_amdgcn_mfma_f32_16x16x32_bf16(ah[rt], bl[ct], acc[rt][ct], 0, 0, 0);
                acc[rt][ct] = __builtin_amdgcn_mfma_f32_16x16x32_bf16(al[rt], bh[ct], acc[rt][ct], 0, 0, 0);
            }
    }

    // ---------------- epilogue: +b2 (, ReLU) -> fp32
    float ca2[4];
#pragma unroll
    for (int ct = 0; ct < 4; ct++) ca2[ct] = b2[wc * 64 + ct * 16 + c];
#pragma unroll
    for (int rt = 0; rt < 4; rt++)
#pragma unroll
        for (int r = 0; r < 4; r++) {
            int row = row0 + wr * 64 + rt * 16 + g * 4 + r;
            if (row < M) {
#pragma unroll
                for (int ct = 0; ct < 4; ct++) {
                    int col = wc * 64 + ct * 16 + c;
                    float v = acc[rt][ct][r] + ca2[ct];
                    if (RELU_OUT) v = fmaxf(v, 0.f);
                    C[(size_t)row * 128 + col] = v;
                }
            }
        }
#undef AS
#undef HS
}

// ----------------------------------------------------------------- pooling
__global__ __launch_bounds__(384) void pool_kernel(const float* __restrict__ x1,
                                                   const float* __restrict__ x2,
                                                   const float* __restrict__ x3,
                                                   const int* __restrict__ batch,
                                                   float* __restrict__ pooled, int n) {
    __shared__ int bs[128];
    int b0 = blockIdx.x * 128;
    int t = threadIdx.x;
    int rows = n - b0; if (rows > 128) rows = 128;
    for (int i = t; i < rows; i += 384) bs[i] = batch[b0 + i];
    __syncthreads();
    const float* src = (t < 128) ? x1 : ((t < 256) ? x2 : x3);
    int ch = t & 127;
    int gcur = bs[0];
    float acc = 0.f;
#pragma unroll 8
    for (int r = 0; r < rows; r++) {
        int gg = bs[r];
        if (gg != gcur) {                       // block-uniform branch
            atomicAdd(&pooled[gcur * 384 + t], acc);
            acc = 0.f;
            gcur = gg;
        }
        acc += src[(size_t)(b0 + r) * 128 + ch];
    }
    atomicAdd(&pooled[gcur * 384 + t], acc);
}

__global__ __launch_bounds__(128) void final_kernel(const float* __restrict__ pooled,
                                                    const int* __restrict__ batch,
                                                    const float* __restrict__ W,
                                                    const float* __restrict__ b,
                                                    float* __restrict__ out, int n) {
    __shared__ float ps[384];
    int gph = blockIdx.x, t = threadIdx.x;
    int lo1 = 0, hi1 = n;
    while (lo1 < hi1) { int mid = (lo1 + hi1) >> 1; if (batch[mid] < gph) lo1 = mid + 1; else hi1 = mid; }
    int start = lo1;
    int lo2 = start, hi2 = n;
    while (lo2 < hi2) { int mid = (lo2 + hi2) >> 1; if (batch[mid] < gph + 1) lo2 = mid + 1; else hi2 = mid; }
    int cnt = lo2 - start;
    float inv = 1.f / (float)(cnt > 0 ? cnt : 1);
    for (int i = t; i < 384; i += 128) ps[i] = pooled[gph * 384 + i] * inv;
    __syncthreads();
    float acc = b[t];
#pragma unroll 8
    for (int k = 0; k < 384; k++) acc += ps[k] * W[k * 128 + t];
    out[gph * 128 + t] = acc;
}

// ------------------------------------------------------------------ launch
extern "C" void kernel_launch(void* const* d_in, const int* in_sizes, int n_in,
                              void* d_out, int out_size, void* d_ws, size_t ws_size,
                              hipStream_t stream) {
    const float* x     = (const float*)d_in[0];
    const int*   edge  = (const int*)d_in[1];
    const int*   batch = (const int*)d_in[2];
    const float* p[32];
    for (int i = 0; i < n_in && i < 32; i++) p[i] = (const float*)d_in[i];
    const float* lin_W = p[27];
    const float* lin_b = p[28];

    char* w = (char*)d_ws;
    auto alloc = [&](size_t bytes) { void* r = (void*)w; w += (bytes + 255) & ~(size_t)255; return r; };
    const size_t PL = (size_t)NNODES * 128;
    ushort* thi   = (ushort*)alloc(PL * 2);
    ushort* tlo   = (ushort*)alloc(PL * 2);
    float* x1     = (float*)alloc(PL * 4);
    float* x2b    = (float*)alloc(PL * 4);
    float* x3b    = (float*)alloc(PL * 4);
    float* pooled = (float*)alloc((size_t)NGRAPHS * 384 * 4);
    int* counts   = (int*)alloc((size_t)NNODES * 4);
    int* cursor   = (int*)alloc((size_t)NNODES * 4);
    int* row_ptr  = (int*)alloc((size_t)(NNODES + 1) * 4);
    int* esrc     = (int*)alloc((size_t)NEDGES * 4);
    int* partials = (int*)alloc(256 * 4);
    ushort* wt_hi = (ushort*)alloc((size_t)6 * 16384 * 2);
    ushort* wt_lo = (ushort*)alloc((size_t)6 * 16384 * 2);

    const int* src = edge;
    const int* dst = edge + NEDGES;

    // --- prep: zero pooled/counts + row_ptr[N] + weight split (1 dispatch)
    prep_kernel<<<484, 256, 0, stream>>>(pooled, counts, row_ptr,
                                         p[3], p[9], p[11], p[17], p[19], p[25],
                                         wt_hi, wt_lo);

    // --- CSR build: 4 dispatches (scan2 folded into scan3)
    int nb = (NNODES + 255) / 256;  // 196
    hist_kernel<<<(NEDGES + 255) / 256, 256, 0, stream>>>(dst, counts, NEDGES);
    scan1_kernel<<<nb, 256, 0, stream>>>(counts, partials, NNODES);
    scan3_kernel<<<nb, 256, 0, stream>>>(counts, partials, row_ptr, cursor, NNODES, nb);
    scatter_kernel<<<(NEDGES + 255) / 256, 256, 0, stream>>>(src, dst, cursor, esrc, NEDGES);

    // --- 3 GIN layers (separate agg + mlp: both R5-proven)
    int mlp_grid = (NNODES + 127) / 128;            // 391
    int agg_grid = (NNODES / 2 * 64 + 255) / 256;   // 6250
    const float* xin = x;
    float* fouts[3] = {x1, x2b, x3b};
    for (int li = 0; li < 3; li++) {
        const float* b1 = p[4 + 8 * li];
        const float* gm = p[5 + 8 * li];
        const float* bt = p[6 + 8 * li];
        const float* rm = p[7 + 8 * li];
        const float* rv = p[8 + 8 * li];
        const float* b2 = p[10 + 8 * li];
        const ushort* w1h = wt_hi + (size_t)(2 * li) * 16384;
        const ushort* w1l = wt_lo + (size_t)(2 * li) * 16384;
        const ushort* w2h = wt_hi + (size_t)(2 * li + 1) * 16384;
        const ushort* w2l = wt_lo + (size_t)(2 * li + 1) * 16384;

        agg_kernel<<<agg_grid, 256, 0, stream>>>(xin, row_ptr, esrc, thi, tlo, NNODES);
        if (li < 2)
            mlp_kernel<true><<<mlp_grid, 256, 0, stream>>>(thi, tlo, w1h, w1l, w2h, w2l,
                                                           b1, gm, bt, rm, rv, b2,
                                                           fouts[li], NNODES);
        else
            mlp_kernel<false><<<mlp_grid, 256, 0, stream>>>(thi, tlo, w1h, w1l, w2h, w2l,
                                                            b1, gm, bt, rm, rv, b2,
                                                            fouts[li], NNODES);
        xin = fouts[li];
    }

    // --- JK-concat mean pool + final linear
    pool_kernel<<<(NNODES + 127) / 128, 384, 0, stream>>>(x1, x2b, x3b, batch, pooled, NNODES);
    final_kernel<<<NGRAPHS, 128, 0, stream>>>(pooled, batch, lin_W, lin_b, (float*)d_out, NNODES);
}

// Round 10
// 414.362 us; speedup vs baseline: 1.5802x; 1.0960x over previous
//
#include <hip/hip_runtime.h>
#include <hip/hip_bf16.h>

#define NNODES 50000
#define NEDGES 600000
#define NGRAPHS 512
#define BN_EPS 1e-5f

typedef short bf16x8 __attribute__((ext_vector_type(8)));
typedef float f32x4 __attribute__((ext_vector_type(4)));

// split fp32 -> hi/lo bf16 (RNE); hi+lo carries ~16 mantissa bits
__device__ __forceinline__ void bf_split(float x, ushort& h, ushort& l) {
    __hip_bfloat16 bh = __float2bfloat16(x);
    float r = x - __bfloat162float(bh);
    __hip_bfloat16 bl = __float2bfloat16(r);
    h = __builtin_bit_cast(ushort, bh);
    l = __builtin_bit_cast(ushort, bl);
}
__device__ __forceinline__ ushort f2b(float x) {
    return __builtin_bit_cast(ushort, __float2bfloat16(x));
}
__device__ __forceinline__ float b2f(ushort u) {
    union { uint i; float f; } c; c.i = ((uint)u) << 16; return c.f;
}

// ------------------------------------------------------------------- prep
// One dispatch: x->bf16 (blocks 0..3124), zero pooled (3125..3316), zero
// counts (3317..3512), wsplit 6 matrices (3513..3608), row_ptr[N] init.
__global__ __launch_bounds__(256) void prep_kernel(
    const float* __restrict__ x, ushort* __restrict__ xh,
    float* __restrict__ pooled, int* __restrict__ counts, int* __restrict__ row_ptr,
    const float* W0, const float* W1, const float* W2, const float* W3,
    const float* W4, const float* W5, ushort* __restrict__ hi, ushort* __restrict__ lo) {
    int b = blockIdx.x, t = threadIdx.x;
    if (b < 3125) {                                 // x: 6.4M floats -> bf16
        int f4 = b * 512 + t * 2;
        float4 a0 = ((const float4*)x)[f4];
        float4 a1 = ((const float4*)x)[f4 + 1];
        ushort4 u0 = {f2b(a0.x), f2b(a0.y), f2b(a0.z), f2b(a0.w)};
        ushort4 u1 = {f2b(a1.x), f2b(a1.y), f2b(a1.z), f2b(a1.w)};
        int e0 = f4 * 4;
        *(ushort4*)(xh + e0) = u0;
        *(ushort4*)(xh + e0 + 4) = u1;
        if (b == 0 && t == 0) row_ptr[NNODES] = NEDGES;
    } else if (b < 3317) {                          // pooled: 512*384 floats
        ((float4*)pooled)[(b - 3125) * 256 + t] = make_float4(0.f, 0.f, 0.f, 0.f);
    } else if (b < 3513) {                          // counts: 50000 ints
        int i = (b - 3317) * 256 + t;
        if (i < NNODES) counts[i] = 0;
    } else {                                        // wsplit: 96 blocks
        int wb = b - 3513;
        const float* Ws[6] = {W0, W1, W2, W3, W4, W5};
        const float* W = Ws[wb >> 4];
        ushort* h = hi + (size_t)(wb >> 4) * 16384;
        ushort* l = lo + (size_t)(wb >> 4) * 16384;
        int chunk = wb & 15;
#pragma unroll
        for (int i = 0; i < 4; i++) {
            int idx = chunk * 1024 + i * 256 + t;
            int n = idx >> 7, k = idx & 127;
            ushort hh, ll;
            bf_split(W[k * 128 + n], hh, ll);
            h[n * 128 + k] = hh;
            l[n * 128 + k] = ll;
        }
    }
}

// ---------------------------------------------------------------- CSR build
__global__ __launch_bounds__(256) void hist_kernel(const int* __restrict__ dst,
                                                   int* __restrict__ counts, int E) {
    int i = blockIdx.x * 256 + threadIdx.x;
    if (i < E) atomicAdd(&counts[dst[i]], 1);
}

__global__ __launch_bounds__(256) void scan1_kernel(const int* __restrict__ counts,
                                                    int* __restrict__ partials, int n) {
    __shared__ int s[256];
    int i = blockIdx.x * 256 + threadIdx.x;
    int v = (i < n) ? counts[i] : 0;
    s[threadIdx.x] = v;
    __syncthreads();
    for (int off = 128; off > 0; off >>= 1) {
        if (threadIdx.x < off) s[threadIdx.x] += s[threadIdx.x + off];
        __syncthreads();
    }
    if (threadIdx.x == 0) partials[blockIdx.x] = s[0];
}

// scan3 with inline base reduction (no scan2 dispatch), nb<=256
__global__ __launch_bounds__(256) void scan3_kernel(const int* __restrict__ counts,
                                                    const int* __restrict__ partials,
                                                    int* __restrict__ row_ptr,
                                                    int* __restrict__ cursor, int n, int nb) {
    __shared__ int s[256];
    __shared__ int base_sh;
    int t = threadIdx.x;
    int pv = (t < (int)blockIdx.x && t < nb) ? partials[t] : 0;
    s[t] = pv;
    __syncthreads();
    for (int off = 128; off > 0; off >>= 1) {
        if (t < off) s[t] += s[t + off];
        __syncthreads();
    }
    if (t == 0) base_sh = s[0];
    __syncthreads();
    int base = base_sh;
    int i = blockIdx.x * 256 + t;
    int v = (i < n) ? counts[i] : 0;
    __syncthreads();
    s[t] = v;
    __syncthreads();
    for (int off = 1; off < 256; off <<= 1) {
        int nv = (t >= off) ? s[t - off] : 0;
        __syncthreads();
        s[t] += nv;
        __syncthreads();
    }
    if (i < n) {
        int ex = base + s[t] - v;   // exclusive
        row_ptr[i] = ex;
        cursor[i] = ex;
    }
}

__global__ __launch_bounds__(256) void scatter_kernel(const int* __restrict__ src,
                                                      const int* __restrict__ dst,
                                                      int* __restrict__ cursor,
                                                      int* __restrict__ esrc, int E) {
    int i = blockIdx.x * 256 + threadIdx.x;
    if (i < E) {
        int p = atomicAdd(&cursor[dst[i]], 1);
        esrc[p] = src[i];
    }
}

// ------------------------------------------------------------- aggregation
// 2 nodes/wave, 32 lanes x 4 channels. NEIGHBORS from bf16 hi-plane only
// (256B rows — halves the 142MB/dispatch L2-miss traffic that pinned agg at
// 47us across R3-R9). SELF term exact: fp32 x (L1) or hi+lo planes (L2/3).
// fp32 accumulate -> exact-sum hi/lo split out (MLP precision unchanged).
template <bool SELF_F32>
__global__ __launch_bounds__(256) void agg_kernel(
    const float* __restrict__ xf,
    const ushort* __restrict__ phi, const ushort* __restrict__ plo,
    const int* __restrict__ rp, const int* __restrict__ esrc,
    ushort* __restrict__ ohi, ushort* __restrict__ olo, int n) {
    int wid  = (blockIdx.x * 256 + threadIdx.x) >> 6;
    int lane = threadIdx.x & 63;
    int node = wid * 2 + (lane >> 5);
    int q = lane & 31;
    if (node >= n) return;
    const ushort4* xh = (const ushort4*)phi;
    float4 acc;
    if (SELF_F32) {
        acc = ((const float4*)xf)[(size_t)node * 32 + q];
    } else {
        ushort4 sh = xh[(size_t)node * 32 + q];
        ushort4 sl = ((const ushort4*)plo)[(size_t)node * 32 + q];
        acc.x = b2f(sh.x) + b2f(sl.x);
        acc.y = b2f(sh.y) + b2f(sl.y);
        acc.z = b2f(sh.z) + b2f(sl.z);
        acc.w = b2f(sh.w) + b2f(sl.w);
    }
    int beg = rp[node], end = rp[node + 1];
    int e = beg;
    for (; e + 8 <= end; e += 8) {
        int i0 = esrc[e],     i1 = esrc[e + 1], i2 = esrc[e + 2], i3 = esrc[e + 3];
        int i4 = esrc[e + 4], i5 = esrc[e + 5], i6 = esrc[e + 6], i7 = esrc[e + 7];
        ushort4 v0 = xh[(size_t)i0 * 32 + q];
        ushort4 v1 = xh[(size_t)i1 * 32 + q];
        ushort4 v2 = xh[(size_t)i2 * 32 + q];
        ushort4 v3 = xh[(size_t)i3 * 32 + q];
        ushort4 v4 = xh[(size_t)i4 * 32 + q];
        ushort4 v5 = xh[(size_t)i5 * 32 + q];
        ushort4 v6 = xh[(size_t)i6 * 32 + q];
        ushort4 v7 = xh[(size_t)i7 * 32 + q];
        acc.x += ((b2f(v0.x) + b2f(v1.x)) + (b2f(v2.x) + b2f(v3.x))) +
                 ((b2f(v4.x) + b2f(v5.x)) + (b2f(v6.x) + b2f(v7.x)));
        acc.y += ((b2f(v0.y) + b2f(v1.y)) + (b2f(v2.y) + b2f(v3.y))) +
                 ((b2f(v4.y) + b2f(v5.y)) + (b2f(v6.y) + b2f(v7.y)));
        acc.z += ((b2f(v0.z) + b2f(v1.z)) + (b2f(v2.z) + b2f(v3.z))) +
                 ((b2f(v4.z) + b2f(v5.z)) + (b2f(v6.z) + b2f(v7.z)));
        acc.w += ((b2f(v0.w) + b2f(v1.w)) + (b2f(v2.w) + b2f(v3.w))) +
                 ((b2f(v4.w) + b2f(v5.w)) + (b2f(v6.w) + b2f(v7.w)));
    }
    for (; e + 2 <= end; e += 2) {
        int i0 = esrc[e], i1 = esrc[e + 1];
        ushort4 v0 = xh[(size_t)i0 * 32 + q];
        ushort4 v1 = xh[(size_t)i1 * 32 + q];
        acc.x += b2f(v0.x) + b2f(v1.x); acc.y += b2f(v0.y) + b2f(v1.y);
        acc.z += b2f(v0.z) + b2f(v1.z); acc.w += b2f(v0.w) + b2f(v1.w);
    }
    for (; e < end; e++) {
        ushort4 v = xh[(size_t)esrc[e] * 32 + q];
        acc.x += b2f(v.x); acc.y += b2f(v.y); acc.z += b2f(v.z); acc.w += b2f(v.w);
    }
    ushort4 hh, ll;
    bf_split(acc.x, hh.x, ll.x);
    bf_split(acc.y, hh.y, ll.y);
    bf_split(acc.z, hh.z, ll.z);
    bf_split(acc.w, hh.w, ll.w);
    *(ushort4*)(ohi + (size_t)node * 128 + q * 4) = hh;
    *(ushort4*)(olo + (size_t)node * 128 + q * 4) = ll;
}

// --------------------------------------------------------------- fused MLP
// (structure R5/R9-proven ~27us) C = act( BN_ReLU( A@W1 ) @ W2 ), 128-row
// tile, split-bf16 MFMA. Output now hi/lo plane pair (same bytes as fp32).
#define HP 136
template <bool RELU_OUT>
__global__ __launch_bounds__(256) void mlp_kernel(
    const ushort* __restrict__ Ahi, const ushort* __restrict__ Alo,
    const ushort* __restrict__ W1hi, const ushort* __restrict__ W1lo,
    const ushort* __restrict__ W2hi, const ushort* __restrict__ W2lo,
    const float* __restrict__ b1, const float* __restrict__ gm,
    const float* __restrict__ bt, const float* __restrict__ rm,
    const float* __restrict__ rv, const float* __restrict__ b2,
    ushort* __restrict__ Chi, ushort* __restrict__ Clo, int M) {
    __shared__ __align__(16) ushort smem[2 * 128 * HP];   // 69632 B
#define AS(b_, p_, o_) smem[(((b_) * 2 + (p_)) << 12) + (o_)]
#define HS(p_, o_) smem[(p_)*128 * HP + (o_)]
    const int t = threadIdx.x;
    const int lane = t & 63;
    const int wv = t >> 6;
    const int wr = wv >> 1, wc = wv & 1;
    const int row0 = blockIdx.x * 128;
    const int g = lane >> 4, c = lane & 15;

    const int m0 = t >> 2,  k80 = (t & 3) * 8;
    const int m1 = m0 + 64;
    int r0 = row0 + m0; if (r0 >= M) r0 = M - 1;
    int r1 = row0 + m1; if (r1 >= M) r1 = M - 1;
    const size_t ga0 = (size_t)r0 * 128 + k80;
    const size_t ga1 = (size_t)r1 * 128 + k80;
    const int la0 = m0 * 32 + k80, la1 = m1 * 32 + k80;

    f32x4 acc[4][4];
#pragma unroll
    for (int i = 0; i < 4; i++)
#pragma unroll
        for (int j = 0; j < 4; j++) acc[i][j] = (f32x4){0.f, 0.f, 0.f, 0.f};

    uint4 ph0 = *(const uint4*)(Ahi + ga0);
    uint4 ph1 = *(const uint4*)(Ahi + ga1);
    uint4 pl0 = *(const uint4*)(Alo + ga0);
    uint4 pl1 = *(const uint4*)(Alo + ga1);
    *(uint4*)&AS(0, 0, la0) = ph0;
    *(uint4*)&AS(0, 0, la1) = ph1;
    *(uint4*)&AS(0, 1, la0) = pl0;
    *(uint4*)&AS(0, 1, la1) = pl1;
    __syncthreads();

    // ---------------- phase 1: A @ W1
    int cur = 0;
    for (int kb = 0; kb < 4; kb++) {
        bf16x8 bh[4], bl[4];
#pragma unroll
        for (int ct = 0; ct < 4; ct++) {
            const size_t wo = (size_t)(wc * 64 + ct * 16 + c) * 128 + kb * 32 + g * 8;
            bh[ct] = *(const bf16x8*)(W1hi + wo);
            bl[ct] = *(const bf16x8*)(W1lo + wo);
        }
        if (kb < 3) {
            const size_t o = (size_t)(kb + 1) * 32;
            ph0 = *(const uint4*)(Ahi + ga0 + o);
            ph1 = *(const uint4*)(Ahi + ga1 + o);
            pl0 = *(const uint4*)(Alo + ga0 + o);
            pl1 = *(const uint4*)(Alo + ga1 + o);
        }
        bf16x8 ah[4], al[4];
#pragma unroll
        for (int rt = 0; rt < 4; rt++) {
            int off = (wr * 64 + rt * 16 + c) * 32 + g * 8;
            ah[rt] = *(bf16x8*)&AS(cur, 0, off);
            al[rt] = *(bf16x8*)&AS(cur, 1, off);
        }
#pragma unroll
        for (int rt = 0; rt < 4; rt++)
#pragma unroll
            for (int ct = 0; ct < 4; ct++) {
                acc[rt][ct] = __builtin_amdgcn_mfma_f32_16x16x32_bf16(ah[rt], bh[ct], acc[rt][ct], 0, 0, 0);
                acc[rt][ct] = __builtin_amdgcn_mfma_f32_16x16x32_bf16(ah[rt], bl[ct], acc[rt][ct], 0, 0, 0);
                acc[rt][ct] = __builtin_amdgcn_mfma_f32_16x16x32_bf16(al[rt], bh[ct], acc[rt][ct], 0, 0, 0);
            }
        if (kb < 3) {
            *(uint4*)&AS(cur ^ 1, 0, la0) = ph0;
            *(uint4*)&AS(cur ^ 1, 0, la1) = ph1;
            *(uint4*)&AS(cur ^ 1, 1, la0) = pl0;
            *(uint4*)&AS(cur ^ 1, 1, la1) = pl1;
        }
        __syncthreads();   // final iter: all As reads done -> H may alias
        cur ^= 1;
    }

    // ---------------- BN + ReLU -> H (hi/lo bf16) in LDS
    {
        float cs[4], ca[4];
#pragma unroll
        for (int ct = 0; ct < 4; ct++) {
            int n = wc * 64 + ct * 16 + c;
            float s = gm[n] * rsqrtf(rv[n] + BN_EPS);
            cs[ct] = s;
            ca[ct] = (b1[n] - rm[n]) * s + bt[n];
        }
#pragma unroll
        for (int rt = 0; rt < 4; rt++)
#pragma unroll
            for (int r = 0; r < 4; r++) {
                int row = wr * 64 + rt * 16 + g * 4 + r;
#pragma unroll
                for (int ct = 0; ct < 4; ct++) {
                    int col = wc * 64 + ct * 16 + c;
                    float v = fmaxf(acc[rt][ct][r] * cs[ct] + ca[ct], 0.f);
                    ushort hh, ll;
                    bf_split(v, hh, ll);
                    HS(0, row * HP + col) = hh;
                    HS(1, row * HP + col) = ll;
                }
            }
    }
    __syncthreads();

    // ---------------- phase 2: H @ W2
#pragma unroll
    for (int i = 0; i < 4; i++)
#pragma unroll
        for (int j = 0; j < 4; j++) acc[i][j] = (f32x4){0.f, 0.f, 0.f, 0.f};

    for (int kb = 0; kb < 4; kb++) {
        bf16x8 bh[4], bl[4];
#pragma unroll
        for (int ct = 0; ct < 4; ct++) {
            const size_t wo = (size_t)(wc * 64 + ct * 16 + c) * 128 + kb * 32 + g * 8;
            bh[ct] = *(const bf16x8*)(W2hi + wo);
            bl[ct] = *(const bf16x8*)(W2lo + wo);
        }
        bf16x8 ah[4], al[4];
#pragma unroll
        for (int rt = 0; rt < 4; rt++) {
            int off = (wr * 64 + rt * 16 + c) * HP + kb * 32 + g * 8;
            ah[rt] = *(bf16x8*)&HS(0, off);
            al[rt] = *(bf16x8*)&HS(1, off);
        }
#pragma unroll
        for (int rt = 0; rt < 4; rt++)
#pragma unroll
            for (int ct = 0; ct < 4; ct++) {
                acc[rt][ct] = __builtin_amdgcn_mfma_f32_16x16x32_bf16(ah[rt], bh[ct], acc[rt][ct], 0, 0, 0);
                acc[rt][ct] = __builtin_amdgcn_mfma_f32_16x16x32_bf16(ah[rt], bl[ct], acc[rt][ct], 0, 0, 0);
                acc[rt][ct] = __builtin_amdgcn_mfma_f32_16x16x32_bf16(al[rt], bh[ct], acc[rt][ct], 0, 0, 0);
            }
    }

    // ---------------- epilogue: +b2 (, ReLU) -> hi/lo planes
    float ca2[4];
#pragma unroll
    for (int ct = 0; ct < 4; ct++) ca2[ct] = b2[wc * 64 + ct * 16 + c];
#pragma unroll
    for (int rt = 0; rt < 4; rt++)
#pragma unroll
        for (int r = 0; r < 4; r++) {
            int row = row0 + wr * 64 + rt * 16 + g * 4 + r;
            if (row < M) {
#pragma unroll
                for (int ct = 0; ct < 4; ct++) {
                    int col = wc * 64 + ct * 16 + c;
                    float v = acc[rt][ct][r] + ca2[ct];
                    if (RELU_OUT) v = fmaxf(v, 0.f);
                    ushort hh, ll;
                    bf_split(v, hh, ll);
                    Chi[(size_t)row * 128 + col] = hh;
                    Clo[(size_t)row * 128 + col] = ll;
                }
            }
        }
#undef AS
#undef HS
}

// ----------------------------------------------------------------- pooling
// reads hi/lo plane pairs; v = hi + lo
__global__ __launch_bounds__(384) void pool_kernel(
    const ushort* __restrict__ x1h, const ushort* __restrict__ x1l,
    const ushort* __restrict__ x2h, const ushort* __restrict__ x2l,
    const ushort* __restrict__ x3h, const ushort* __restrict__ x3l,
    const int* __restrict__ batch, float* __restrict__ pooled, int n) {
    __shared__ int bs[128];
    int b0 = blockIdx.x * 128;
    int t = threadIdx.x;
    int rows = n - b0; if (rows > 128) rows = 128;
    for (int i = t; i < rows; i += 384) bs[i] = batch[b0 + i];
    __syncthreads();
    const ushort* ph = (t < 128) ? x1h : ((t < 256) ? x2h : x3h);
    const ushort* pl = (t < 128) ? x1l : ((t < 256) ? x2l : x3l);
    int ch = t & 127;
    int gcur = bs[0];
    float acc = 0.f;
#pragma unroll 8
    for (int r = 0; r < rows; r++) {
        int gg = bs[r];
        if (gg != gcur) {                       // block-uniform branch
            atomicAdd(&pooled[gcur * 384 + t], acc);
            acc = 0.f;
            gcur = gg;
        }
        size_t o = (size_t)(b0 + r) * 128 + ch;
        acc += b2f(ph[o]) + b2f(pl[o]);
    }
    atomicAdd(&pooled[gcur * 384 + t], acc);
}

__global__ __launch_bounds__(128) void final_kernel(const float* __restrict__ pooled,
                                                    const int* __restrict__ batch,
                                                    const float* __restrict__ W,
                                                    const float* __restrict__ b,
                                                    float* __restrict__ out, int n) {
    __shared__ float ps[384];
    int gph = blockIdx.x, t = threadIdx.x;
    int lo1 = 0, hi1 = n;
    while (lo1 < hi1) { int mid = (lo1 + hi1) >> 1; if (batch[mid] < gph) lo1 = mid + 1; else hi1 = mid; }
    int start = lo1;
    int lo2 = start, hi2 = n;
    while (lo2 < hi2) { int mid = (lo2 + hi2) >> 1; if (batch[mid] < gph + 1) lo2 = mid + 1; else hi2 = mid; }
    int cnt = lo2 - start;
    float inv = 1.f / (float)(cnt > 0 ? cnt : 1);
    for (int i = t; i < 384; i += 128) ps[i] = pooled[gph * 384 + i] * inv;
    __syncthreads();
    float acc = b[t];
#pragma unroll 8
    for (int k = 0; k < 384; k++) acc += ps[k] * W[k * 128 + t];
    out[gph * 128 + t] = acc;
}

// ------------------------------------------------------------------ launch
extern "C" void kernel_launch(void* const* d_in, const int* in_sizes, int n_in,
                              void* d_out, int out_size, void* d_ws, size_t ws_size,
                              hipStream_t stream) {
    const float* x     = (const float*)d_in[0];
    const int*   edge  = (const int*)d_in[1];
    const int*   batch = (const int*)d_in[2];
    const float* p[32];
    for (int i = 0; i < n_in && i < 32; i++) p[i] = (const float*)d_in[i];
    const float* lin_W = p[27];
    const float* lin_b = p[28];

    char* w = (char*)d_ws;
    auto alloc = [&](size_t bytes) { void* r = (void*)w; w += (bytes + 255) & ~(size_t)255; return r; };
    const size_t PL = (size_t)NNODES * 128;
    ushort* thi   = (ushort*)alloc(PL * 2);   // agg out planes
    ushort* tlo   = (ushort*)alloc(PL * 2);
    ushort* xh0   = (ushort*)alloc(PL * 2);   // bf16(x); dead after agg L1
    ushort* p1h   = (ushort*)alloc(PL * 2);
    ushort* p1l   = (ushort*)alloc(PL * 2);
    ushort* p2h   = xh0;                      // alias: xh0 dead before mlp L2 writes
    ushort* p2l   = (ushort*)alloc(PL * 2);
    ushort* p3h   = (ushort*)alloc(PL * 2);
    ushort* p3l   = (ushort*)alloc(PL * 2);
    float* pooled = (float*)alloc((size_t)NGRAPHS * 384 * 4);
    int* counts   = (int*)alloc((size_t)NNODES * 4);
    int* cursor   = (int*)alloc((size_t)NNODES * 4);
    int* row_ptr  = (int*)alloc((size_t)(NNODES + 1) * 4);
    int* esrc     = (int*)alloc((size_t)NEDGES * 4);
    int* partials = (int*)alloc(256 * 4);
    ushort* wt_hi = (ushort*)alloc((size_t)6 * 16384 * 2);
    ushort* wt_lo = (ushort*)alloc((size_t)6 * 16384 * 2);

    const int* src = edge;
    const int* dst = edge + NEDGES;

    // --- prep: x->bf16, zero pooled/counts, row_ptr[N], wsplit (1 dispatch)
    prep_kernel<<<3609, 256, 0, stream>>>(x, xh0, pooled, counts, row_ptr,
                                          p[3], p[9], p[11], p[17], p[19], p[25],
                                          wt_hi, wt_lo);

    // --- CSR build: 4 dispatches
    int nb = (NNODES + 255) / 256;  // 196
    hist_kernel<<<(NEDGES + 255) / 256, 256, 0, stream>>>(dst, counts, NEDGES);
    scan1_kernel<<<nb, 256, 0, stream>>>(counts, partials, NNODES);
    scan3_kernel<<<nb, 256, 0, stream>>>(counts, partials, row_ptr, cursor, NNODES, nb);
    scatter_kernel<<<(NEDGES + 255) / 256, 256, 0, stream>>>(src, dst, cursor, esrc, NEDGES);

    // --- 3 GIN layers
    int mlp_grid = (NNODES + 127) / 128;            // 391
    int agg_grid = (NNODES / 2 * 64 + 255) / 256;   // 6250

    // layer 1: self fp32 x, neighbors xh0
    agg_kernel<true><<<agg_grid, 256, 0, stream>>>(x, xh0, nullptr, row_ptr, esrc,
                                                   thi, tlo, NNODES);
    mlp_kernel<true><<<mlp_grid, 256, 0, stream>>>(thi, tlo,
        wt_hi + 0 * 16384, wt_lo + 0 * 16384, wt_hi + 1 * 16384, wt_lo + 1 * 16384,
        p[4], p[5], p[6], p[7], p[8], p[10], p1h, p1l, NNODES);
    // layer 2
    agg_kernel<false><<<agg_grid, 256, 0, stream>>>(nullptr, p1h, p1l, row_ptr, esrc,
                                                    thi, tlo, NNODES);
    mlp_kernel<true><<<mlp_grid, 256, 0, stream>>>(thi, tlo,
        wt_hi + 2 * 16384, wt_lo + 2 * 16384, wt_hi + 3 * 16384, wt_lo + 3 * 16384,
        p[12], p[13], p[14], p[15], p[16], p[18], p2h, p2l, NNODES);
    // layer 3 (no relu)
    agg_kernel<false><<<agg_grid, 256, 0, stream>>>(nullptr, p2h, p2l, row_ptr, esrc,
                                                    thi, tlo, NNODES);
    mlp_kernel<false><<<mlp_grid, 256, 0, stream>>>(thi, tlo,
        wt_hi + 4 * 16384, wt_lo + 4 * 16384, wt_hi + 5 * 16384, wt_lo + 5 * 16384,
        p[20], p[21], p[22], p[23], p[24], p[26], p3h, p3l, NNODES);

    // --- JK-concat mean pool + final linear
    pool_kernel<<<(NNODES + 127) / 128, 384, 0, stream>>>(p1h, p1l, p2h, p2l, p3h, p3l,
                                                          batch, pooled, NNODES);
    final_kernel<<<NGRAPHS, 128, 0, stream>>>(pooled, batch, lin_W, lin_b,
                                              (float*)d_out, NNODES);
}

// Round 11
// 403.192 us; speedup vs baseline: 1.6239x; 1.0277x over previous
//
#include <hip/hip_runtime.h>
#include <hip/hip_bf16.h>

#define NNODES 50000
#define NEDGES 600000
#define NGRAPHS 512
#define BN_EPS 1e-5f

typedef short bf16x8 __attribute__((ext_vector_type(8)));
typedef float f32x4 __attribute__((ext_vector_type(4)));

// split fp32 -> hi/lo bf16 (RNE); hi+lo carries ~16 mantissa bits
__device__ __forceinline__ void bf_split(float x, ushort& h, ushort& l) {
    __hip_bfloat16 bh = __float2bfloat16(x);
    float r = x - __bfloat162float(bh);
    __hip_bfloat16 bl = __float2bfloat16(r);
    h = __builtin_bit_cast(ushort, bh);
    l = __builtin_bit_cast(ushort, bl);
}
__device__ __forceinline__ ushort f2b(float x) {
    return __builtin_bit_cast(ushort, __float2bfloat16(x));
}
__device__ __forceinline__ float b2f(ushort u) {
    union { uint i; float f; } c; c.i = ((uint)u) << 16; return c.f;
}

// ------------------------------------------------------------------- prep
// One dispatch: x->bf16 (blocks 0..3124), zero pooled (3125..3316), zero
// counts (3317..3512), wsplit 6 matrices (3513..3608), row_ptr[N] init.
__global__ __launch_bounds__(256) void prep_kernel(
    const float* __restrict__ x, ushort* __restrict__ xh,
    float* __restrict__ pooled, int* __restrict__ counts, int* __restrict__ row_ptr,
    const float* W0, const float* W1, const float* W2, const float* W3,
    const float* W4, const float* W5, ushort* __restrict__ hi, ushort* __restrict__ lo) {
    int b = blockIdx.x, t = threadIdx.x;
    if (b < 3125) {                                 // x: 6.4M floats -> bf16
        int f4 = b * 512 + t * 2;
        float4 a0 = ((const float4*)x)[f4];
        float4 a1 = ((const float4*)x)[f4 + 1];
        ushort4 u0 = {f2b(a0.x), f2b(a0.y), f2b(a0.z), f2b(a0.w)};
        ushort4 u1 = {f2b(a1.x), f2b(a1.y), f2b(a1.z), f2b(a1.w)};
        int e0 = f4 * 4;
        *(ushort4*)(xh + e0) = u0;
        *(ushort4*)(xh + e0 + 4) = u1;
        if (b == 0 && t == 0) row_ptr[NNODES] = NEDGES;
    } else if (b < 3317) {                          // pooled: 512*384 floats
        ((float4*)pooled)[(b - 3125) * 256 + t] = make_float4(0.f, 0.f, 0.f, 0.f);
    } else if (b < 3513) {                          // counts: 50000 ints
        int i = (b - 3317) * 256 + t;
        if (i < NNODES) counts[i] = 0;
    } else {                                        // wsplit: 96 blocks
        int wb = b - 3513;
        const float* Ws[6] = {W0, W1, W2, W3, W4, W5};
        const float* W = Ws[wb >> 4];
        ushort* h = hi + (size_t)(wb >> 4) * 16384;
        ushort* l = lo + (size_t)(wb >> 4) * 16384;
        int chunk = wb & 15;
#pragma unroll
        for (int i = 0; i < 4; i++) {
            int idx = chunk * 1024 + i * 256 + t;
            int n = idx >> 7, k = idx & 127;
            ushort hh, ll;
            bf_split(W[k * 128 + n], hh, ll);
            h[n * 128 + k] = hh;
            l[n * 128 + k] = ll;
        }
    }
}

// ---------------------------------------------------------------- CSR build
__global__ __launch_bounds__(256) void hist_kernel(const int* __restrict__ dst,
                                                   int* __restrict__ counts, int E) {
    int i = blockIdx.x * 256 + threadIdx.x;
    if (i < E) atomicAdd(&counts[dst[i]], 1);
}

__global__ __launch_bounds__(256) void scan1_kernel(const int* __restrict__ counts,
                                                    int* __restrict__ partials, int n) {
    __shared__ int s[256];
    int i = blockIdx.x * 256 + threadIdx.x;
    int v = (i < n) ? counts[i] : 0;
    s[threadIdx.x] = v;
    __syncthreads();
    for (int off = 128; off > 0; off >>= 1) {
        if (threadIdx.x < off) s[threadIdx.x] += s[threadIdx.x + off];
        __syncthreads();
    }
    if (threadIdx.x == 0) partials[blockIdx.x] = s[0];
}

// scan3 with inline base reduction (no scan2 dispatch), nb<=256
__global__ __launch_bounds__(256) void scan3_kernel(const int* __restrict__ counts,
                                                    const int* __restrict__ partials,
                                                    int* __restrict__ row_ptr,
                                                    int* __restrict__ cursor, int n, int nb) {
    __shared__ int s[256];
    __shared__ int base_sh;
    int t = threadIdx.x;
    int pv = (t < (int)blockIdx.x && t < nb) ? partials[t] : 0;
    s[t] = pv;
    __syncthreads();
    for (int off = 128; off > 0; off >>= 1) {
        if (t < off) s[t] += s[t + off];
        __syncthreads();
    }
    if (t == 0) base_sh = s[0];
    __syncthreads();
    int base = base_sh;
    int i = blockIdx.x * 256 + t;
    int v = (i < n) ? counts[i] : 0;
    __syncthreads();
    s[t] = v;
    __syncthreads();
    for (int off = 1; off < 256; off <<= 1) {
        int nv = (t >= off) ? s[t - off] : 0;
        __syncthreads();
        s[t] += nv;
        __syncthreads();
    }
    if (i < n) {
        int ex = base + s[t] - v;   // exclusive
        row_ptr[i] = ex;
        cursor[i] = ex;
    }
}

__global__ __launch_bounds__(256) void scatter_kernel(const int* __restrict__ src,
                                                      const int* __restrict__ dst,
                                                      int* __restrict__ cursor,
                                                      int* __restrict__ esrc, int E) {
    int i = blockIdx.x * 256 + threadIdx.x;
    if (i < E) {
        int p = atomicAdd(&cursor[dst[i]], 1);
        esrc[p] = src[i];
    }
}

// ------------------------------------------------------------- aggregation
// (R10-proven, <46us) 2 nodes/wave, 32 lanes x 4 ch. Neighbors from bf16
// hi-plane (256B rows); self exact (fp32 x or hi+lo). fp32 accumulate ->
// exact-sum hi/lo split out.
template <bool SELF_F32>
__global__ __launch_bounds__(256) void agg_kernel(
    const float* __restrict__ xf,
    const ushort* __restrict__ phi, const ushort* __restrict__ plo,
    const int* __restrict__ rp, const int* __restrict__ esrc,
    ushort* __restrict__ ohi, ushort* __restrict__ olo, int n) {
    int wid  = (blockIdx.x * 256 + threadIdx.x) >> 6;
    int lane = threadIdx.x & 63;
    int node = wid * 2 + (lane >> 5);
    int q = lane & 31;
    if (node >= n) return;
    const ushort4* xh = (const ushort4*)phi;
    float4 acc;
    if (SELF_F32) {
        acc = ((const float4*)xf)[(size_t)node * 32 + q];
    } else {
        ushort4 sh = xh[(size_t)node * 32 + q];
        ushort4 sl = ((const ushort4*)plo)[(size_t)node * 32 + q];
        acc.x = b2f(sh.x) + b2f(sl.x);
        acc.y = b2f(sh.y) + b2f(sl.y);
        acc.z = b2f(sh.z) + b2f(sl.z);
        acc.w = b2f(sh.w) + b2f(sl.w);
    }
    int beg = rp[node], end = rp[node + 1];
    int e = beg;
    for (; e + 8 <= end; e += 8) {
        int i0 = esrc[e],     i1 = esrc[e + 1], i2 = esrc[e + 2], i3 = esrc[e + 3];
        int i4 = esrc[e + 4], i5 = esrc[e + 5], i6 = esrc[e + 6], i7 = esrc[e + 7];
        ushort4 v0 = xh[(size_t)i0 * 32 + q];
        ushort4 v1 = xh[(size_t)i1 * 32 + q];
        ushort4 v2 = xh[(size_t)i2 * 32 + q];
        ushort4 v3 = xh[(size_t)i3 * 32 + q];
        ushort4 v4 = xh[(size_t)i4 * 32 + q];
        ushort4 v5 = xh[(size_t)i5 * 32 + q];
        ushort4 v6 = xh[(size_t)i6 * 32 + q];
        ushort4 v7 = xh[(size_t)i7 * 32 + q];
        acc.x += ((b2f(v0.x) + b2f(v1.x)) + (b2f(v2.x) + b2f(v3.x))) +
                 ((b2f(v4.x) + b2f(v5.x)) + (b2f(v6.x) + b2f(v7.x)));
        acc.y += ((b2f(v0.y) + b2f(v1.y)) + (b2f(v2.y) + b2f(v3.y))) +
                 ((b2f(v4.y) + b2f(v5.y)) + (b2f(v6.y) + b2f(v7.y)));
        acc.z += ((b2f(v0.z) + b2f(v1.z)) + (b2f(v2.z) + b2f(v3.z))) +
                 ((b2f(v4.z) + b2f(v5.z)) + (b2f(v6.z) + b2f(v7.z)));
        acc.w += ((b2f(v0.w) + b2f(v1.w)) + (b2f(v2.w) + b2f(v3.w))) +
                 ((b2f(v4.w) + b2f(v5.w)) + (b2f(v6.w) + b2f(v7.w)));
    }
    for (; e + 2 <= end; e += 2) {
        int i0 = esrc[e], i1 = esrc[e + 1];
        ushort4 v0 = xh[(size_t)i0 * 32 + q];
        ushort4 v1 = xh[(size_t)i1 * 32 + q];
        acc.x += b2f(v0.x) + b2f(v1.x); acc.y += b2f(v0.y) + b2f(v1.y);
        acc.z += b2f(v0.z) + b2f(v1.z); acc.w += b2f(v0.w) + b2f(v1.w);
    }
    for (; e < end; e++) {
        ushort4 v = xh[(size_t)esrc[e] * 32 + q];
        acc.x += b2f(v.x); acc.y += b2f(v.y); acc.z += b2f(v.z); acc.w += b2f(v.w);
    }
    ushort4 hh, ll;
    bf_split(acc.x, hh.x, ll.x);
    bf_split(acc.y, hh.y, ll.y);
    bf_split(acc.z, hh.z, ll.z);
    bf_split(acc.w, hh.w, ll.w);
    *(ushort4*)(ohi + (size_t)node * 128 + q * 4) = hh;
    *(ushort4*)(olo + (size_t)node * 128 + q * 4) = ll;
}

// --------------------------------------------------------------- fused MLP
// (R5/R9/R10-proven ~27us) C = act( BN_ReLU( A@W1 ) @ W2 ), 128-row tile,
// split-bf16 MFMA. Output hi/lo plane pair.
#define HP 136
template <bool RELU_OUT>
__global__ __launch_bounds__(256) void mlp_kernel(
    const ushort* __restrict__ Ahi, const ushort* __restrict__ Alo,
    const ushort* __restrict__ W1hi, const ushort* __restrict__ W1lo,
    const ushort* __restrict__ W2hi, const ushort* __restrict__ W2lo,
    const float* __restrict__ b1, const float* __restrict__ gm,
    const float* __restrict__ bt, const float* __restrict__ rm,
    const float* __restrict__ rv, const float* __restrict__ b2,
    ushort* __restrict__ Chi, ushort* __restrict__ Clo, int M) {
    __shared__ __align__(16) ushort smem[2 * 128 * HP];   // 69632 B
#define AS(b_, p_, o_) smem[(((b_) * 2 + (p_)) << 12) + (o_)]
#define HS(p_, o_) smem[(p_)*128 * HP + (o_)]
    const int t = threadIdx.x;
    const int lane = t & 63;
    const int wv = t >> 6;
    const int wr = wv >> 1, wc = wv & 1;
    const int row0 = blockIdx.x * 128;
    const int g = lane >> 4, c = lane & 15;

    const int m0 = t >> 2,  k80 = (t & 3) * 8;
    const int m1 = m0 + 64;
    int r0 = row0 + m0; if (r0 >= M) r0 = M - 1;
    int r1 = row0 + m1; if (r1 >= M) r1 = M - 1;
    const size_t ga0 = (size_t)r0 * 128 + k80;
    const size_t ga1 = (size_t)r1 * 128 + k80;
    const int la0 = m0 * 32 + k80, la1 = m1 * 32 + k80;

    f32x4 acc[4][4];
#pragma unroll
    for (int i = 0; i < 4; i++)
#pragma unroll
        for (int j = 0; j < 4; j++) acc[i][j] = (f32x4){0.f, 0.f, 0.f, 0.f};

    uint4 ph0 = *(const uint4*)(Ahi + ga0);
    uint4 ph1 = *(const uint4*)(Ahi + ga1);
    uint4 pl0 = *(const uint4*)(Alo + ga0);
    uint4 pl1 = *(const uint4*)(Alo + ga1);
    *(uint4*)&AS(0, 0, la0) = ph0;
    *(uint4*)&AS(0, 0, la1) = ph1;
    *(uint4*)&AS(0, 1, la0) = pl0;
    *(uint4*)&AS(0, 1, la1) = pl1;
    __syncthreads();

    // ---------------- phase 1: A @ W1
    int cur = 0;
    for (int kb = 0; kb < 4; kb++) {
        bf16x8 bh[4], bl[4];
#pragma unroll
        for (int ct = 0; ct < 4; ct++) {
            const size_t wo = (size_t)(wc * 64 + ct * 16 + c) * 128 + kb * 32 + g * 8;
            bh[ct] = *(const bf16x8*)(W1hi + wo);
            bl[ct] = *(const bf16x8*)(W1lo + wo);
        }
        if (kb < 3) {
            const size_t o = (size_t)(kb + 1) * 32;
            ph0 = *(const uint4*)(Ahi + ga0 + o);
            ph1 = *(const uint4*)(Ahi + ga1 + o);
            pl0 = *(const uint4*)(Alo + ga0 + o);
            pl1 = *(const uint4*)(Alo + ga1 + o);
        }
        bf16x8 ah[4], al[4];
#pragma unroll
        for (int rt = 0; rt < 4; rt++) {
            int off = (wr * 64 + rt * 16 + c) * 32 + g * 8;
            ah[rt] = *(bf16x8*)&AS(cur, 0, off);
            al[rt] = *(bf16x8*)&AS(cur, 1, off);
        }
#pragma unroll
        for (int rt = 0; rt < 4; rt++)
#pragma unroll
            for (int ct = 0; ct < 4; ct++) {
                acc[rt][ct] = __builtin_amdgcn_mfma_f32_16x16x32_bf16(ah[rt], bh[ct], acc[rt][ct], 0, 0, 0);
                acc[rt][ct] = __builtin_amdgcn_mfma_f32_16x16x32_bf16(ah[rt], bl[ct], acc[rt][ct], 0, 0, 0);
                acc[rt][ct] = __builtin_amdgcn_mfma_f32_16x16x32_bf16(al[rt], bh[ct], acc[rt][ct], 0, 0, 0);
            }
        if (kb < 3) {
            *(uint4*)&AS(cur ^ 1, 0, la0) = ph0;
            *(uint4*)&AS(cur ^ 1, 0, la1) = ph1;
            *(uint4*)&AS(cur ^ 1, 1, la0) = pl0;
            *(uint4*)&AS(cur ^ 1, 1, la1) = pl1;
        }
        __syncthreads();   // final iter: all As reads done -> H may alias
        cur ^= 1;
    }

    // ---------------- BN + ReLU -> H (hi/lo bf16) in LDS
    {
        float cs[4], ca[4];
#pragma unroll
        for (int ct = 0; ct < 4; ct++) {
            int n = wc * 64 + ct * 16 + c;
            float s = gm[n] * rsqrtf(rv[n] + BN_EPS);
            cs[ct] = s;
            ca[ct] = (b1[n] - rm[n]) * s + bt[n];
        }
#pragma unroll
        for (int rt = 0; rt < 4; rt++)
#pragma unroll
            for (int r = 0; r < 4; r++) {
                int row = wr * 64 + rt * 16 + g * 4 + r;
#pragma unroll
                for (int ct = 0; ct < 4; ct++) {
                    int col = wc * 64 + ct * 16 + c;
                    float v = fmaxf(acc[rt][ct][r] * cs[ct] + ca[ct], 0.f);
                    ushort hh, ll;
                    bf_split(v, hh, ll);
                    HS(0, row * HP + col) = hh;
                    HS(1, row * HP + col) = ll;
                }
            }
    }
    __syncthreads();

    // ---------------- phase 2: H @ W2
#pragma unroll
    for (int i = 0; i < 4; i++)
#pragma unroll
        for (int j = 0; j < 4; j++) acc[i][j] = (f32x4){0.f, 0.f, 0.f, 0.f};

    for (int kb = 0; kb < 4; kb++) {
        bf16x8 bh[4], bl[4];
#pragma unroll
        for (int ct = 0; ct < 4; ct++) {
            const size_t wo = (size_t)(wc * 64 + ct * 16 + c) * 128 + kb * 32 + g * 8;
            bh[ct] = *(const bf16x8*)(W2hi + wo);
            bl[ct] = *(const bf16x8*)(W2lo + wo);
        }
        bf16x8 ah[4], al[4];
#pragma unroll
        for (int rt = 0; rt < 4; rt++) {
            int off = (wr * 64 + rt * 16 + c) * HP + kb * 32 + g * 8;
            ah[rt] = *(bf16x8*)&HS(0, off);
            al[rt] = *(bf16x8*)&HS(1, off);
        }
#pragma unroll
        for (int rt = 0; rt < 4; rt++)
#pragma unroll
            for (int ct = 0; ct < 4; ct++) {
                acc[rt][ct] = __builtin_amdgcn_mfma_f32_16x16x32_bf16(ah[rt], bh[ct], acc[rt][ct], 0, 0, 0);
                acc[rt][ct] = __builtin_amdgcn_mfma_f32_16x16x32_bf16(ah[rt], bl[ct], acc[rt][ct], 0, 0, 0);
                acc[rt][ct] = __builtin_amdgcn_mfma_f32_16x16x32_bf16(al[rt], bh[ct], acc[rt][ct], 0, 0, 0);
            }
    }

    // ---------------- epilogue: +b2 (, ReLU) -> hi/lo planes
    float ca2[4];
#pragma unroll
    for (int ct = 0; ct < 4; ct++) ca2[ct] = b2[wc * 64 + ct * 16 + c];
#pragma unroll
    for (int rt = 0; rt < 4; rt++)
#pragma unroll
        for (int r = 0; r < 4; r++) {
            int row = row0 + wr * 64 + rt * 16 + g * 4 + r;
            if (row < M) {
#pragma unroll
                for (int ct = 0; ct < 4; ct++) {
                    int col = wc * 64 + ct * 16 + c;
                    float v = acc[rt][ct][r] + ca2[ct];
                    if (RELU_OUT) v = fmaxf(v, 0.f);
                    ushort hh, ll;
                    bf_split(v, hh, ll);
                    Chi[(size_t)row * 128 + col] = hh;
                    Clo[(size_t)row * 128 + col] = ll;
                }
            }
        }
#undef AS
#undef HS
}

// ----------------------------------------------------------------- pooling
// 32 rows/block (1563 blocks: R10's 391-block version was grid-starved at
// 21% occupancy, 46us). Run-length accumulate; ~1.3 boundary atomics per
// block per channel-slot.
__global__ __launch_bounds__(384) void pool_kernel(
    const ushort* __restrict__ x1h, const ushort* __restrict__ x1l,
    const ushort* __restrict__ x2h, const ushort* __restrict__ x2l,
    const ushort* __restrict__ x3h, const ushort* __restrict__ x3l,
    const int* __restrict__ batch, float* __restrict__ pooled, int n) {
    __shared__ int bs[32];
    int b0 = blockIdx.x * 32;
    int t = threadIdx.x;
    int rows = n - b0; if (rows > 32) rows = 32;
    if (t < rows) bs[t] = batch[b0 + t];
    __syncthreads();
    const ushort* ph = (t < 128) ? x1h : ((t < 256) ? x2h : x3h);
    const ushort* pl = (t < 128) ? x1l : ((t < 256) ? x2l : x3l);
    int ch = t & 127;
    int gcur = bs[0];
    float acc = 0.f;
#pragma unroll 8
    for (int r = 0; r < rows; r++) {
        int gg = bs[r];
        if (gg != gcur) {                       // block-uniform branch
            atomicAdd(&pooled[gcur * 384 + t], acc);
            acc = 0.f;
            gcur = gg;
        }
        size_t o = (size_t)(b0 + r) * 128 + ch;
        acc += b2f(ph[o]) + b2f(pl[o]);
    }
    atomicAdd(&pooled[gcur * 384 + t], acc);
}

__global__ __launch_bounds__(128) void final_kernel(const float* __restrict__ pooled,
                                                    const int* __restrict__ batch,
                                                    const float* __restrict__ W,
                                                    const float* __restrict__ b,
                                                    float* __restrict__ out, int n) {
    __shared__ float ps[384];
    int gph = blockIdx.x, t = threadIdx.x;
    int lo1 = 0, hi1 = n;
    while (lo1 < hi1) { int mid = (lo1 + hi1) >> 1; if (batch[mid] < gph) lo1 = mid + 1; else hi1 = mid; }
    int start = lo1;
    int lo2 = start, hi2 = n;
    while (lo2 < hi2) { int mid = (lo2 + hi2) >> 1; if (batch[mid] < gph + 1) lo2 = mid + 1; else hi2 = mid; }
    int cnt = lo2 - start;
    float inv = 1.f / (float)(cnt > 0 ? cnt : 1);
    for (int i = t; i < 384; i += 128) ps[i] = pooled[gph * 384 + i] * inv;
    __syncthreads();
    float acc = b[t];
#pragma unroll 8
    for (int k = 0; k < 384; k++) acc += ps[k] * W[k * 128 + t];
    out[gph * 128 + t] = acc;
}

// ------------------------------------------------------------------ launch
extern "C" void kernel_launch(void* const* d_in, const int* in_sizes, int n_in,
                              void* d_out, int out_size, void* d_ws, size_t ws_size,
                              hipStream_t stream) {
    const float* x     = (const float*)d_in[0];
    const int*   edge  = (const int*)d_in[1];
    const int*   batch = (const int*)d_in[2];
    const float* p[32];
    for (int i = 0; i < n_in && i < 32; i++) p[i] = (const float*)d_in[i];
    const float* lin_W = p[27];
    const float* lin_b = p[28];

    char* w = (char*)d_ws;
    auto alloc = [&](size_t bytes) { void* r = (void*)w; w += (bytes + 255) & ~(size_t)255; return r; };
    const size_t PL = (size_t)NNODES * 128;
    ushort* thi   = (ushort*)alloc(PL * 2);   // agg out planes
    ushort* tlo   = (ushort*)alloc(PL * 2);
    ushort* xh0   = (ushort*)alloc(PL * 2);   // bf16(x); dead after agg L1
    ushort* p1h   = (ushort*)alloc(PL * 2);
    ushort* p1l   = (ushort*)alloc(PL * 2);
    ushort* p2h   = xh0;                      // alias: xh0 dead before mlp L2 writes
    ushort* p2l   = (ushort*)alloc(PL * 2);
    ushort* p3h   = (ushort*)alloc(PL * 2);
    ushort* p3l   = (ushort*)alloc(PL * 2);
    float* pooled = (float*)alloc((size_t)NGRAPHS * 384 * 4);
    int* counts   = (int*)alloc((size_t)NNODES * 4);
    int* cursor   = (int*)alloc((size_t)NNODES * 4);
    int* row_ptr  = (int*)alloc((size_t)(NNODES + 1) * 4);
    int* esrc     = (int*)alloc((size_t)NEDGES * 4);
    int* partials = (int*)alloc(256 * 4);
    ushort* wt_hi = (ushort*)alloc((size_t)6 * 16384 * 2);
    ushort* wt_lo = (ushort*)alloc((size_t)6 * 16384 * 2);

    const int* src = edge;
    const int* dst = edge + NEDGES;

    // --- prep: x->bf16, zero pooled/counts, row_ptr[N], wsplit (1 dispatch)
    prep_kernel<<<3609, 256, 0, stream>>>(x, xh0, pooled, counts, row_ptr,
                                          p[3], p[9], p[11], p[17], p[19], p[25],
                                          wt_hi, wt_lo);

    // --- CSR build: 4 dispatches
    int nb = (NNODES + 255) / 256;  // 196
    hist_kernel<<<(NEDGES + 255) / 256, 256, 0, stream>>>(dst, counts, NEDGES);
    scan1_kernel<<<nb, 256, 0, stream>>>(counts, partials, NNODES);
    scan3_kernel<<<nb, 256, 0, stream>>>(counts, partials, row_ptr, cursor, NNODES, nb);
    scatter_kernel<<<(NEDGES + 255) / 256, 256, 0, stream>>>(src, dst, cursor, esrc, NEDGES);

    // --- 3 GIN layers
    int mlp_grid = (NNODES + 127) / 128;            // 391
    int agg_grid = (NNODES / 2 * 64 + 255) / 256;   // 6250

    // layer 1: self fp32 x, neighbors xh0
    agg_kernel<true><<<agg_grid, 256, 0, stream>>>(x, xh0, nullptr, row_ptr, esrc,
                                                   thi, tlo, NNODES);
    mlp_kernel<true><<<mlp_grid, 256, 0, stream>>>(thi, tlo,
        wt_hi + 0 * 16384, wt_lo + 0 * 16384, wt_hi + 1 * 16384, wt_lo + 1 * 16384,
        p[4], p[5], p[6], p[7], p[8], p[10], p1h, p1l, NNODES);
    // layer 2
    agg_kernel<false><<<agg_grid, 256, 0, stream>>>(nullptr, p1h, p1l, row_ptr, esrc,
                                                    thi, tlo, NNODES);
    mlp_kernel<true><<<mlp_grid, 256, 0, stream>>>(thi, tlo,
        wt_hi + 2 * 16384, wt_lo + 2 * 16384, wt_hi + 3 * 16384, wt_lo + 3 * 16384,
        p[12], p[13], p[14], p[15], p[16], p[18], p2h, p2l, NNODES);
    // layer 3 (no relu)
    agg_kernel<false><<<agg_grid, 256, 0, stream>>>(nullptr, p2h, p2l, row_ptr, esrc,
                                                    thi, tlo, NNODES);
    mlp_kernel<false><<<mlp_grid, 256, 0, stream>>>(thi, tlo,
        wt_hi + 4 * 16384, wt_lo + 4 * 16384, wt_hi + 5 * 16384, wt_lo + 5 * 16384,
        p[20], p[21], p[22], p[23], p[24], p[26], p3h, p3l, NNODES);

    // --- JK-concat mean pool + final linear
    pool_kernel<<<(NNODES + 31) / 32, 384, 0, stream>>>(p1h, p1l, p2h, p2l, p3h, p3l,
                                                        batch, pooled, NNODES);
    final_kernel<<<NGRAPHS, 128, 0, stream>>>(pooled, batch, lin_W, lin_b,
                                              (float*)d_out, NNODES);
}